// Round 6
// baseline (216.777 us; speedup 1.0000x reference)
//
#include <hip/hip_runtime.h>

#define B_ 4
#define S_ 2048
#define D_ 1024
#define H_ 16
#define HD_ 64
#define M_ (B_*S_)      // 8192 rows
#define NQKV_ (3*D_)    // 3072

typedef _Float16 f16;
typedef __attribute__((ext_vector_type(4))) _Float16 f16x4;
typedef __attribute__((ext_vector_type(8))) _Float16 f16x8;
typedef __attribute__((ext_vector_type(4))) float f32x4;

__device__ __forceinline__ void gload_lds16(const void* g, void* lds) {
  __builtin_amdgcn_global_load_lds(
      (const __attribute__((address_space(1))) void*)g,
      (__attribute__((address_space(3))) void*)lds, 16, 0, 0);
}

// ---------------- cast fp32 -> fp16, 8 elems/thread ----------------
__global__ void cast_kernel(const float* __restrict__ in, f16* __restrict__ out) {
  size_t i = (size_t)(blockIdx.x * 256 + threadIdx.x) * 8;
  float4 a = *reinterpret_cast<const float4*>(in + i);
  float4 b = *reinterpret_cast<const float4*>(in + i + 4);
  f16x8 o;
  o[0] = (f16)a.x; o[1] = (f16)a.y; o[2] = (f16)a.z; o[3] = (f16)a.w;
  o[4] = (f16)b.x; o[5] = (f16)b.y; o[6] = (f16)b.z; o[7] = (f16)b.w;
  *reinterpret_cast<f16x8*>(out + i) = o;
}

// ---------------- RoPE trig table: tab[s][t] = {cos,sin}(pos[s]*invf(t))
__global__ void trig_kernel(const int* __restrict__ pos, float2* __restrict__ tab) {
  int idx = blockIdx.x * 256 + threadIdx.x;   // S_*32 threads
  int s = idx >> 5, t = idx & 31;
  float p = (float)pos[s];
  float invf = exp2f((float)t * -0.4152410118609203f);  // -log2(10000)/32
  float sn, cs;
  sincosf(p * invf, &sn, &cs);
  tab[idx] = float2{cs, sn};
}

// ---------------- GEMM C[m,n] = sum_k A[m,k]*Bt[n,k], swapped-operand
// D-fragment: col=lr -> output row m, row-reg (orow+r) -> output col n,
// so each lane holds 4 CONSECUTIVE n. (Mapping verified by attn S^T.)
// MODE 0 (QKV): n in [0,1024)=Q -> rope*qs -> q(B,H,S,hd);
//               [1024,2048)=K -> rope -> k(B,H,S,hd);
//               [2048,3072)=V -> transposed write vt(B,H,hd,S).
// MODE 1: fp32 C row-major, float4 stores.
template <int MODE>
__global__ __launch_bounds__(256)
void gemm_bt(const f16* __restrict__ A, const f16* __restrict__ Bt,
             void* __restrict__ Cout, const float2* __restrict__ tab,
             f16* __restrict__ kout, f16* __restrict__ vtout,
             int M, int N, int K) {
  __shared__ __align__(16) f16 As[128 * 64];
  __shared__ __align__(16) f16 Bs[128 * 64];
  const int tid = threadIdx.x;
  const int w = tid >> 6, l = tid & 63;
  const int nM = M >> 7;
  const int bm = (blockIdx.x % nM) << 7;
  const int bn = (blockIdx.x / nM) << 7;
  const int wr = (w >> 1) << 6;   // wave row offset in tile
  const int wc = (w & 1) << 6;    // wave col offset in tile
  const int lr = l & 15;
  const int lk = (l >> 4) << 3;
  const int orow = (l >> 4) << 2;
  const int srow = tid >> 3;            // staging row within 32-row chunk
  const int sc8 = (tid & 7) * 8;        // staging col (elems)

  f32x4 acc[4][4];
  #pragma unroll
  for (int i = 0; i < 4; ++i)
    #pragma unroll
    for (int j = 0; j < 4; ++j) acc[i][j] = f32x4{0.f, 0.f, 0.f, 0.f};

  for (int k0 = 0; k0 < K; k0 += 64) {
    __syncthreads();
    #pragma unroll
    for (int i = 0; i < 4; ++i) {
      gload_lds16(A + (size_t)(bm + i * 32 + srow) * K + k0 + sc8,
                  (void*)(As + (i * 256 + w * 64) * 8));
      gload_lds16(Bt + (size_t)(bn + i * 32 + srow) * K + k0 + sc8,
                  (void*)(Bs + (i * 256 + w * 64) * 8));
    }
    __syncthreads();
    #pragma unroll
    for (int t = 0; t < 2; ++t) {
      f16x8 af[4], bfr[4];
      #pragma unroll
      for (int mi = 0; mi < 4; ++mi)
        af[mi] = *reinterpret_cast<const f16x8*>(As + (wr + mi * 16 + lr) * 64 + t * 32 + lk);
      #pragma unroll
      for (int ni = 0; ni < 4; ++ni)
        bfr[ni] = *reinterpret_cast<const f16x8*>(Bs + (wc + ni * 16 + lr) * 64 + t * 32 + lk);
      #pragma unroll
      for (int mi = 0; mi < 4; ++mi)
        #pragma unroll
        for (int ni = 0; ni < 4; ++ni)
          acc[mi][ni] = __builtin_amdgcn_mfma_f32_16x16x32_f16(bfr[ni], af[mi], acc[mi][ni], 0, 0, 0);
    }
  }

  if (MODE == 0) {
    const int which = bn >> 10;                 // uniform per block
    const int h = ((bn + wc) >> 6) & (H_ - 1);  // uniform per wave
    if (which < 2) {                            // Q or K: fused RoPE
      f16* dst = which ? kout : (f16*)Cout;
      const float qs = which ? 1.0f : 0.125f * 1.4426950408889634f;  // (1/8)*log2e
      #pragma unroll
      for (int mi = 0; mi < 4; ++mi) {
        int m = bm + wr + mi * 16 + lr;
        int b = m >> 11, s = m & (S_ - 1);
        size_t rowbase = ((size_t)(b * H_ + h) * S_ + s) * HD_;
        const float4* trow = reinterpret_cast<const float4*>(tab + (size_t)s * 32);
        #pragma unroll
        for (int ni = 0; ni < 4; ++ni) {
          int d0 = ni * 16 + orow;              // multiple of 4
          float4 cssn = trow[d0 >> 2];          // {cos(t0),sin(t0),cos(t0+1),sin(t0+1)}
          float x0 = acc[mi][ni][0], x1 = acc[mi][ni][1];
          float x2 = acc[mi][ni][2], x3 = acc[mi][ni][3];
          f16x4 ov;
          ov[0] = (f16)((x0 * cssn.x - x1 * cssn.y) * qs);
          ov[1] = (f16)((x1 * cssn.x + x0 * cssn.y) * qs);
          ov[2] = (f16)((x2 * cssn.z - x3 * cssn.w) * qs);
          ov[3] = (f16)((x3 * cssn.z + x2 * cssn.w) * qs);
          *reinterpret_cast<f16x4*>(&dst[rowbase + d0]) = ov;
        }
      }
    } else {                                    // V: direct transposed write
      #pragma unroll
      for (int mi = 0; mi < 4; ++mi) {
        int m = bm + wr + mi * 16 + lr;
        int b = m >> 11, s = m & (S_ - 1);
        size_t base = (size_t)(b * H_ + h) * (HD_ * S_) + s;
        #pragma unroll
        for (int ni = 0; ni < 4; ++ni)
          #pragma unroll
          for (int r = 0; r < 4; ++r)
            vtout[base + (size_t)(ni * 16 + orow + r) * S_] = (f16)acc[mi][ni][r];
      }
    }
  } else {
    float* C = (float*)Cout;
    #pragma unroll
    for (int mi = 0; mi < 4; ++mi) {
      int m = bm + wr + mi * 16 + lr;
      #pragma unroll
      for (int ni = 0; ni < 4; ++ni) {
        int n = bn + wc + ni * 16 + orow;
        *reinterpret_cast<float4*>(&C[(size_t)m * N + n]) =
            float4{acc[mi][ni][0], acc[mi][ni][1], acc[mi][ni][2], acc[mi][ni][3]};
      }
    }
  }
}

// ---------------- flash attention (causal), swapped-operand form ----
// grid: (S/64) * (B*H), heavy q-tiles first. 4 waves, each owns 16
// q-rows. S^T = mfma(K,Q): lane holds a full q-row of scores. Q
// pre-scaled by (1/8)*log2e -> exp2 domain. Ks/Vs XOR-swizzled.
// 2-phase pipeline (T3-minimum): double-buffered K/V staging; tile
// t+1's global_load_lds issued BEFORE computing tile t; the single
// barrier (with its vmcnt(0) drain) comes AFTER compute, so load
// latency hides under softmax+MFMA and barriers drop 2->1 per iter.
__global__ __launch_bounds__(256)
void attn_kernel(const f16* __restrict__ q, const f16* __restrict__ k,
                 const f16* __restrict__ vt, f16* __restrict__ attn_out) {
  __shared__ __align__(16) f16 Ks[2][64 * 64];
  __shared__ __align__(16) f16 Vs[2][64 * 64];   // [d][kv]
  __shared__ __align__(16) f16 Ps[4][16 * 72];
  const int tid = threadIdx.x, w = tid >> 6, l = tid & 63;
  const int lr = l & 15, lk = (l >> 4) << 3, orow = (l >> 4) << 2;
  const int bh = blockIdx.x & 63;
  const int qt = 31 - (int)(blockIdx.x >> 6); // heavy tiles first
  const int q0 = qt << 6;
  const size_t bhoff = (size_t)bh * (S_ * HD_);
  const size_t vtoff = (size_t)bh * (HD_ * S_);
  const int srow = tid >> 3;
  const int sc8 = (tid & 7) * 8;
  const int ssw = sc8 ^ ((srow & 7) << 3);    // swizzled source col (elems)
  const int swz = (lr & 7) << 3;              // read-side XOR (row&7)<<3
  const int h = bh & (H_ - 1), b = bh >> 4;
  const int qg = q0 + w * 16 + lr;            // this lane's q-row

  f16x8 qf[2];
  #pragma unroll
  for (int t = 0; t < 2; ++t)
    qf[t] = *reinterpret_cast<const f16x8*>(q + bhoff + (size_t)qg * HD_ + t * 32 + lk);

  f32x4 o[4];
  float m_run = -1e30f, l_run = 0.f;
  #pragma unroll
  for (int i = 0; i < 4; ++i) o[i] = f32x4{0.f, 0.f, 0.f, 0.f};

  const int ntiles = qt + 1;

  // prologue: stage tile 0 into buffer 0
  {
    const int kv0 = 0;
    #pragma unroll
    for (int i = 0; i < 2; ++i) {
      gload_lds16(k + bhoff + (size_t)(kv0 + i * 32 + srow) * HD_ + ssw,
                  (void*)(&Ks[0][(i * 256 + w * 64) * 8]));
      gload_lds16(vt + vtoff + (size_t)(i * 32 + srow) * S_ + kv0 + ssw,
                  (void*)(&Vs[0][(i * 256 + w * 64) * 8]));
    }
  }
  __syncthreads();   // vmcnt(0) drain + barrier: tile 0 resident

  int cur = 0;
  for (int it = 0; it < ntiles; ++it) {
    // prefetch tile it+1 into the other buffer (wave-uniform guard)
    if (it + 1 < ntiles) {
      const int kv1 = (it + 1) << 6;
      #pragma unroll
      for (int i = 0; i < 2; ++i) {
        gload_lds16(k + bhoff + (size_t)(kv1 + i * 32 + srow) * HD_ + ssw,
                    (void*)(&Ks[cur ^ 1][(i * 256 + w * 64) * 8]));
        gload_lds16(vt + vtoff + (size_t)(i * 32 + srow) * S_ + kv1 + ssw,
                    (void*)(&Vs[cur ^ 1][(i * 256 + w * 64) * 8]));
      }
    }

    const int kv0 = it << 6;
    const f16* Ksc = Ks[cur];
    const f16* Vsc = Vs[cur];

    // S^T: D[col=q=lr][row=kv=ni*16+orow+r]
    f32x4 sacc[4];
    #pragma unroll
    for (int ni = 0; ni < 4; ++ni) sacc[ni] = f32x4{0.f, 0.f, 0.f, 0.f};
    #pragma unroll
    for (int t = 0; t < 2; ++t) {
      #pragma unroll
      for (int ni = 0; ni < 4; ++ni) {
        f16x8 kf = *reinterpret_cast<const f16x8*>(Ksc + (ni * 16 + lr) * 64 + ((t * 32 + lk) ^ swz));
        sacc[ni] = __builtin_amdgcn_mfma_f32_16x16x32_f16(kf, qf[t], sacc[ni], 0, 0, 0);
      }
    }
    if (it == ntiles - 1) {   // diagonal tile: causal mask (kv in rows)
      #pragma unroll
      for (int ni = 0; ni < 4; ++ni) {
        #pragma unroll
        for (int r = 0; r < 4; ++r) {
          int kvg = kv0 + ni * 16 + orow + r;
          if (kvg > qg) sacc[ni][r] = -1e30f;
        }
      }
    }

    // online softmax: lane-local row (16 vals) + 2 shuffles
    f32x4 m4 = sacc[0];
    #pragma unroll
    for (int ni = 1; ni < 4; ++ni)
      #pragma unroll
      for (int r = 0; r < 4; ++r) m4[r] = fmaxf(m4[r], sacc[ni][r]);
    float mloc = fmaxf(fmaxf(m4[0], m4[1]), fmaxf(m4[2], m4[3]));
    mloc = fmaxf(mloc, __shfl_xor(mloc, 16));
    mloc = fmaxf(mloc, __shfl_xor(mloc, 32));
    float mn = fmaxf(m_run, mloc);
    float scale = exp2f(m_run - mn);
    m_run = mn;
    #pragma unroll
    for (int ni = 0; ni < 4; ++ni)
      #pragma unroll
      for (int r = 0; r < 4; ++r) sacc[ni][r] = exp2f(sacc[ni][r] - mn);
    f32x4 s4 = sacc[0];
    #pragma unroll
    for (int ni = 1; ni < 4; ++ni)
      #pragma unroll
      for (int r = 0; r < 4; ++r) s4[r] += sacc[ni][r];
    float sloc = (s4[0] + s4[1]) + (s4[2] + s4[3]);
    sloc += __shfl_xor(sloc, 16);
    sloc += __shfl_xor(sloc, 32);
    l_run = l_run * scale + sloc;
    #pragma unroll
    for (int ni = 0; ni < 4; ++ni)
      #pragma unroll
      for (int r = 0; r < 4; ++r) o[ni][r] *= scale;

    // P^T -> LDS (wave-private; program-order lgkmcnt, no barrier)
    #pragma unroll
    for (int ni = 0; ni < 4; ++ni) {
      f16x4 pk;
      #pragma unroll
      for (int r = 0; r < 4; ++r) pk[r] = (f16)sacc[ni][r];
      *reinterpret_cast<f16x4*>(&Ps[w][lr * 72 + ni * 16 + orow]) = pk;
    }

    // O^T += V^T * P^T
    #pragma unroll
    for (int t = 0; t < 2; ++t) {
      f16x8 pf = *reinterpret_cast<const f16x8*>(&Ps[w][lr * 72 + t * 32 + lk]);
      #pragma unroll
      for (int ni = 0; ni < 4; ++ni) {
        f16x8 vf = *reinterpret_cast<const f16x8*>(Vsc + (ni * 16 + lr) * 64 + ((t * 32 + lk) ^ swz));
        o[ni] = __builtin_amdgcn_mfma_f32_16x16x32_f16(vf, pf, o[ni], 0, 0, 0);
      }
    }

    // single barrier: drains prefetch vmcnt + protects buf reuse
    __syncthreads();
    cur ^= 1;
  }

  // epilogue: O^T = [col=q=lr][row=d=ni*16+orow+r] -> packed stores
  float rl = 1.0f / l_run;
  #pragma unroll
  for (int ni = 0; ni < 4; ++ni) {
    f16x4 ov;
    #pragma unroll
    for (int r = 0; r < 4; ++r) ov[r] = (f16)(o[ni][r] * rl);
    *reinterpret_cast<f16x4*>(
        &attn_out[(size_t)(b * S_ + qg) * D_ + h * HD_ + ni * 16 + orow]) = ov;
  }
}

// ---------------- launch --------------------------------------------
extern "C" void kernel_launch(void* const* d_in, const int* in_sizes, int n_in,
                              void* d_out, int out_size, void* d_ws, size_t ws_size,
                              hipStream_t stream) {
  const float* x    = (const float*)d_in[0];
  const int*   pos  = (const int*)d_in[1];
  const float* wqkv = (const float*)d_in[2];
  const float* wo   = (const float*)d_in[3];
  float* out = (float*)d_out;

  const size_t BHSD = (size_t)B_ * H_ * S_ * HD_;   // 8388608
  f16* xb    = (f16*)d_ws;                 // M_*D_
  f16* wqkvb = xb + (size_t)M_ * D_;       // NQKV_*D_
  f16* wob   = wqkvb + (size_t)NQKV_ * D_; // D_*D_
  f16* qb    = wob + (size_t)D_ * D_;      // BHSD
  f16* kb    = qb + BHSD;                  // BHSD
  f16* vtb   = kb + BHSD;                  // BHSD (B,H,hd,S)
  f16* attnb = vtb + BHSD;                 // BHSD
  float2* tab = (float2*)(attnb + BHSD);   // S_*32 float2 = 512 KB
  // total ~92 MB of d_ws

  cast_kernel<<<(M_ * D_) / 2048, 256, 0, stream>>>(x, xb);
  cast_kernel<<<(NQKV_ * D_) / 2048, 256, 0, stream>>>(wqkv, wqkvb);
  cast_kernel<<<(D_ * D_) / 2048, 256, 0, stream>>>(wo, wob);
  trig_kernel<<<(S_ * 32) / 256, 256, 0, stream>>>(pos, tab);

  gemm_bt<0><<<(M_ / 128) * (NQKV_ / 128), 256, 0, stream>>>(
      xb, wqkvb, (void*)qb, tab, kb, vtb, M_, NQKV_, D_);

  attn_kernel<<<64 * 32, 256, 0, stream>>>(qb, kb, vtb, attnb);

  gemm_bt<1><<<(M_ / 128) * (D_ / 128), 256, 0, stream>>>(
      attnb, wob, (void*)out, nullptr, nullptr, nullptr, M_, D_, D_);
}

// Round 7
// 207.016 us; speedup vs baseline: 1.0472x; 1.0472x over previous
//
#include <hip/hip_runtime.h>

#define B_ 4
#define S_ 2048
#define D_ 1024
#define H_ 16
#define HD_ 64
#define M_ (B_*S_)      // 8192 rows
#define NQKV_ (3*D_)    // 3072

typedef _Float16 f16;
typedef __attribute__((ext_vector_type(4))) _Float16 f16x4;
typedef __attribute__((ext_vector_type(8))) _Float16 f16x8;
typedef __attribute__((ext_vector_type(4))) float f32x4;
typedef __attribute__((ext_vector_type(16))) float f32x16;

__device__ __forceinline__ void gload_lds16(const void* g, void* lds) {
  __builtin_amdgcn_global_load_lds(
      (const __attribute__((address_space(1))) void*)g,
      (__attribute__((address_space(3))) void*)lds, 16, 0, 0);
}

// ---------------- cast fp32 -> fp16, 8 elems/thread ----------------
__global__ void cast_kernel(const float* __restrict__ in, f16* __restrict__ out) {
  size_t i = (size_t)(blockIdx.x * 256 + threadIdx.x) * 8;
  float4 a = *reinterpret_cast<const float4*>(in + i);
  float4 b = *reinterpret_cast<const float4*>(in + i + 4);
  f16x8 o;
  o[0] = (f16)a.x; o[1] = (f16)a.y; o[2] = (f16)a.z; o[3] = (f16)a.w;
  o[4] = (f16)b.x; o[5] = (f16)b.y; o[6] = (f16)b.z; o[7] = (f16)b.w;
  *reinterpret_cast<f16x8*>(out + i) = o;
}

// ---------------- RoPE trig table: tab[s][t] = {cos,sin}(pos[s]*invf(t))
__global__ void trig_kernel(const int* __restrict__ pos, float2* __restrict__ tab) {
  int idx = blockIdx.x * 256 + threadIdx.x;   // S_*32 threads
  int s = idx >> 5, t = idx & 31;
  float p = (float)pos[s];
  float invf = exp2f((float)t * -0.4152410118609203f);  // -log2(10000)/32
  float sn, cs;
  sincosf(p * invf, &sn, &cs);
  tab[idx] = float2{cs, sn};
}

// ---------------- GEMM C[m,n] = sum_k A[m,k]*Bt[n,k], swapped-operand
// D-fragment: col=lr -> output row m, row-reg (orow+r) -> output col n,
// so each lane holds 4 CONSECUTIVE n. (Mapping verified by attn S^T.)
// MODE 0 (QKV): n in [0,1024)=Q -> rope*qs -> q(B,H,S,hd);
//               [1024,2048)=K -> rope -> k(B,H,S,hd);
//               [2048,3072)=V -> transposed write vt(B,H,hd,S).
// MODE 1: fp32 C row-major, float4 stores.
template <int MODE>
__global__ __launch_bounds__(256)
void gemm_bt(const f16* __restrict__ A, const f16* __restrict__ Bt,
             void* __restrict__ Cout, const float2* __restrict__ tab,
             f16* __restrict__ kout, f16* __restrict__ vtout,
             int M, int N, int K) {
  __shared__ __align__(16) f16 As[128 * 64];
  __shared__ __align__(16) f16 Bs[128 * 64];
  const int tid = threadIdx.x;
  const int w = tid >> 6, l = tid & 63;
  const int nM = M >> 7;
  const int bm = (blockIdx.x % nM) << 7;
  const int bn = (blockIdx.x / nM) << 7;
  const int wr = (w >> 1) << 6;   // wave row offset in tile
  const int wc = (w & 1) << 6;    // wave col offset in tile
  const int lr = l & 15;
  const int lk = (l >> 4) << 3;
  const int orow = (l >> 4) << 2;
  const int srow = tid >> 3;            // staging row within 32-row chunk
  const int sc8 = (tid & 7) * 8;        // staging col (elems)

  f32x4 acc[4][4];
  #pragma unroll
  for (int i = 0; i < 4; ++i)
    #pragma unroll
    for (int j = 0; j < 4; ++j) acc[i][j] = f32x4{0.f, 0.f, 0.f, 0.f};

  for (int k0 = 0; k0 < K; k0 += 64) {
    __syncthreads();
    #pragma unroll
    for (int i = 0; i < 4; ++i) {
      gload_lds16(A + (size_t)(bm + i * 32 + srow) * K + k0 + sc8,
                  (void*)(As + (i * 256 + w * 64) * 8));
      gload_lds16(Bt + (size_t)(bn + i * 32 + srow) * K + k0 + sc8,
                  (void*)(Bs + (i * 256 + w * 64) * 8));
    }
    __syncthreads();
    #pragma unroll
    for (int t = 0; t < 2; ++t) {
      f16x8 af[4], bfr[4];
      #pragma unroll
      for (int mi = 0; mi < 4; ++mi)
        af[mi] = *reinterpret_cast<const f16x8*>(As + (wr + mi * 16 + lr) * 64 + t * 32 + lk);
      #pragma unroll
      for (int ni = 0; ni < 4; ++ni)
        bfr[ni] = *reinterpret_cast<const f16x8*>(Bs + (wc + ni * 16 + lr) * 64 + t * 32 + lk);
      #pragma unroll
      for (int mi = 0; mi < 4; ++mi)
        #pragma unroll
        for (int ni = 0; ni < 4; ++ni)
          acc[mi][ni] = __builtin_amdgcn_mfma_f32_16x16x32_f16(bfr[ni], af[mi], acc[mi][ni], 0, 0, 0);
    }
  }

  if (MODE == 0) {
    const int which = bn >> 10;                 // uniform per block
    const int h = ((bn + wc) >> 6) & (H_ - 1);  // uniform per wave
    if (which < 2) {                            // Q or K: fused RoPE
      f16* dst = which ? kout : (f16*)Cout;
      const float qs = which ? 1.0f : 0.125f * 1.4426950408889634f;  // (1/8)*log2e
      #pragma unroll
      for (int mi = 0; mi < 4; ++mi) {
        int m = bm + wr + mi * 16 + lr;
        int b = m >> 11, s = m & (S_ - 1);
        size_t rowbase = ((size_t)(b * H_ + h) * S_ + s) * HD_;
        const float4* trow = reinterpret_cast<const float4*>(tab + (size_t)s * 32);
        #pragma unroll
        for (int ni = 0; ni < 4; ++ni) {
          int d0 = ni * 16 + orow;              // multiple of 4
          float4 cssn = trow[d0 >> 2];          // {cos(t0),sin(t0),cos(t0+1),sin(t0+1)}
          float x0 = acc[mi][ni][0], x1 = acc[mi][ni][1];
          float x2 = acc[mi][ni][2], x3 = acc[mi][ni][3];
          f16x4 ov;
          ov[0] = (f16)((x0 * cssn.x - x1 * cssn.y) * qs);
          ov[1] = (f16)((x1 * cssn.x + x0 * cssn.y) * qs);
          ov[2] = (f16)((x2 * cssn.z - x3 * cssn.w) * qs);
          ov[3] = (f16)((x3 * cssn.z + x2 * cssn.w) * qs);
          *reinterpret_cast<f16x4*>(&dst[rowbase + d0]) = ov;
        }
      }
    } else {                                    // V: direct transposed write
      #pragma unroll
      for (int mi = 0; mi < 4; ++mi) {
        int m = bm + wr + mi * 16 + lr;
        int b = m >> 11, s = m & (S_ - 1);
        size_t base = (size_t)(b * H_ + h) * (HD_ * S_) + s;
        #pragma unroll
        for (int ni = 0; ni < 4; ++ni)
          #pragma unroll
          for (int r = 0; r < 4; ++r)
            vtout[base + (size_t)(ni * 16 + orow + r) * S_] = (f16)acc[mi][ni][r];
      }
    }
  } else {
    float* C = (float*)Cout;
    #pragma unroll
    for (int mi = 0; mi < 4; ++mi) {
      int m = bm + wr + mi * 16 + lr;
      #pragma unroll
      for (int ni = 0; ni < 4; ++ni) {
        int n = bn + wc + ni * 16 + orow;
        *reinterpret_cast<float4*>(&C[(size_t)m * N + n]) =
            float4{acc[mi][ni][0], acc[mi][ni][1], acc[mi][ni][2], acc[mi][ni][3]};
      }
    }
  }
}

// ---------------- flash attention (causal), 32x32 MFMA form ---------
// grid: 16 q-tiles (128 rows) x 64 bh, heavy first. 4 waves x 32
// q-rows each; KVBLK=64. S^T = mfma_32x32x16(K, Q): lane holds a full
// q-row (32 scores) -> softmax = in-reg tree + ONE shuffle (l ^ 32).
// Each wave reads K/V tile once for 2x the q-rows of the old 16x16
// form -> LDS bytes/score halved. Waves fully above the diagonal skip
// compute (wave-uniform). Q pre-scaled by (1/8)*log2e -> exp2 domain.
// Ks/Vs/P XOR-swizzled (col ^= (row&7)<<3) via pre-swizzled gload src
// + swizzled ds accesses (both-sides rule).
// Layouts (32x32x16): A row=lane&31, k=(lane>>5)*8+j (analog of the
// verified 16x16x32 map); B col=lane&31, same k; C/D col=lane&31,
// row=(reg&3)+8*(reg>>2)+4*(lane>>5) [m74/m101].
__global__ __launch_bounds__(256, 4)
void attn_kernel(const f16* __restrict__ q, const f16* __restrict__ k,
                 const f16* __restrict__ vt, f16* __restrict__ attn_out) {
  __shared__ __align__(16) f16 Ks[64 * 64];
  __shared__ __align__(16) f16 Vs[64 * 64];     // [d][kv]
  __shared__ __align__(16) f16 Ps[4][32 * 64];  // per-wave P[q][kv]
  const int tid = threadIdx.x, wq = tid >> 6, l = tid & 63;
  const int lq = l & 31, hi = l >> 5;
  const int bh = blockIdx.x & 63;
  const int qt = 15 - (int)(blockIdx.x >> 6);   // heavy tiles first
  const int q0 = qt << 7;
  const size_t bhoff = (size_t)bh * (S_ * HD_);
  const size_t vtoff = (size_t)bh * (HD_ * S_);
  const int srow = tid >> 3;
  const int sc8 = (tid & 7) * 8;
  const int ssw = sc8 ^ ((srow & 7) << 3);      // swizzled source col
  const int swz = (lq & 7) << 3;                // read-side XOR
  const int h = bh & (H_ - 1), b = bh >> 4;
  const int wqmin = q0 + wq * 32;
  const int qrow = wqmin + lq;                  // this lane's q-row

  // Q fragments: B-operand, 4 hd-steps of 16: hd = s*16 + hi*8 + j
  f16x8 qf[4];
  #pragma unroll
  for (int s = 0; s < 4; ++s)
    qf[s] = *reinterpret_cast<const f16x8*>(q + bhoff + (size_t)qrow * HD_ + s * 16 + hi * 8);

  f32x16 o[2];
  float m_run = -1e30f, l_run = 0.f;
  #pragma unroll
  for (int i = 0; i < 2; ++i)
    #pragma unroll
    for (int r = 0; r < 16; ++r) o[i][r] = 0.f;

  f16* Pw = &Ps[wq][0];
  const int ntiles = 2 * qt + 2;
  for (int it = 0; it < ntiles; ++it) {
    const int kv0 = it << 6;
    __syncthreads();
    #pragma unroll
    for (int i = 0; i < 2; ++i) {
      gload_lds16(k + bhoff + (size_t)(kv0 + i * 32 + srow) * HD_ + ssw,
                  (void*)(Ks + (i * 256 + wq * 64) * 8));
      gload_lds16(vt + vtoff + (size_t)(i * 32 + srow) * S_ + kv0 + ssw,
                  (void*)(Vs + (i * 256 + wq * 64) * 8));
    }
    __syncthreads();

    if (kv0 <= wqmin + 31) {   // wave-uniform causal skip
      // S^T: D[col=q=lq][row=kv32], two kv-halves
      f32x16 sacc[2];
      #pragma unroll
      for (int kh = 0; kh < 2; ++kh) {
        #pragma unroll
        for (int r = 0; r < 16; ++r) sacc[kh][r] = 0.f;
        #pragma unroll
        for (int s = 0; s < 4; ++s) {
          f16x8 kf = *reinterpret_cast<const f16x8*>(
              Ks + (kh * 32 + lq) * 64 + ((s * 16 + hi * 8) ^ swz));
          sacc[kh] = __builtin_amdgcn_mfma_f32_32x32x16_f16(kf, qf[s], sacc[kh], 0, 0, 0);
        }
      }
      if (kv0 + 63 >= wqmin) {   // diagonal straddle: element mask
        #pragma unroll
        for (int kh = 0; kh < 2; ++kh)
          #pragma unroll
          for (int r = 0; r < 16; ++r) {
            int kvg = kv0 + kh * 32 + (r & 3) + 8 * (r >> 2) + 4 * hi;
            if (kvg > qrow) sacc[kh][r] = -1e30f;
          }
      }

      // online softmax: 32 lane-local scores + 1 shuffle (l <-> l^32)
      float mloc = -1e30f;
      #pragma unroll
      for (int kh = 0; kh < 2; ++kh)
        #pragma unroll
        for (int r = 0; r < 16; ++r) mloc = fmaxf(mloc, sacc[kh][r]);
      mloc = fmaxf(mloc, __shfl_xor(mloc, 32));
      float mn = fmaxf(m_run, mloc);
      float scale = exp2f(m_run - mn);
      m_run = mn;
      float sloc = 0.f;
      #pragma unroll
      for (int kh = 0; kh < 2; ++kh)
        #pragma unroll
        for (int r = 0; r < 16; ++r) {
          sacc[kh][r] = exp2f(sacc[kh][r] - mn);
          sloc += sacc[kh][r];
        }
      sloc += __shfl_xor(sloc, 32);
      l_run = l_run * scale + sloc;
      #pragma unroll
      for (int i = 0; i < 2; ++i)
        #pragma unroll
        for (int r = 0; r < 16; ++r) o[i][r] *= scale;

      // P[q][kv] -> LDS (wave-private; program-order lgkmcnt, no barrier)
      #pragma unroll
      for (int kh = 0; kh < 2; ++kh)
        #pragma unroll
        for (int qd = 0; qd < 4; ++qd) {
          f16x4 pk;
          #pragma unroll
          for (int r = 0; r < 4; ++r) pk[r] = (f16)sacc[kh][qd * 4 + r];
          int kvb = kh * 32 + qd * 8 + hi * 4;
          *reinterpret_cast<f16x4*>(&Pw[lq * 64 + (kvb ^ swz)]) = pk;
        }

      // O^T += V^T @ P^T  (A=V^T rows d, B=P^T cols q)
      f16x8 pf[4];
      #pragma unroll
      for (int s2 = 0; s2 < 4; ++s2)
        pf[s2] = *reinterpret_cast<const f16x8*>(&Pw[lq * 64 + ((s2 * 16 + hi * 8) ^ swz)]);
      #pragma unroll
      for (int dh = 0; dh < 2; ++dh)
        #pragma unroll
        for (int s2 = 0; s2 < 4; ++s2) {
          f16x8 vf = *reinterpret_cast<const f16x8*>(
              Vs + (dh * 32 + lq) * 64 + ((s2 * 16 + hi * 8) ^ swz));
          o[dh] = __builtin_amdgcn_mfma_f32_32x32x16_f16(vf, pf[s2], o[dh], 0, 0, 0);
        }
    }
  }

  // epilogue: O^T[d][q]: d=(reg&3)+8*(reg>>2)+4*hi+32*dh, q=lq
  float rl = 1.0f / l_run;
  #pragma unroll
  for (int dh = 0; dh < 2; ++dh)
    #pragma unroll
    for (int qd = 0; qd < 4; ++qd) {
      f16x4 ov;
      #pragma unroll
      for (int r = 0; r < 4; ++r) ov[r] = (f16)(o[dh][qd * 4 + r] * rl);
      int d0 = dh * 32 + qd * 8 + hi * 4;
      *reinterpret_cast<f16x4*>(
          &attn_out[(size_t)(b * S_ + qrow) * D_ + h * HD_ + d0]) = ov;
    }
}

// ---------------- launch --------------------------------------------
extern "C" void kernel_launch(void* const* d_in, const int* in_sizes, int n_in,
                              void* d_out, int out_size, void* d_ws, size_t ws_size,
                              hipStream_t stream) {
  const float* x    = (const float*)d_in[0];
  const int*   pos  = (const int*)d_in[1];
  const float* wqkv = (const float*)d_in[2];
  const float* wo   = (const float*)d_in[3];
  float* out = (float*)d_out;

  const size_t BHSD = (size_t)B_ * H_ * S_ * HD_;   // 8388608
  f16* xb    = (f16*)d_ws;                 // M_*D_
  f16* wqkvb = xb + (size_t)M_ * D_;       // NQKV_*D_
  f16* wob   = wqkvb + (size_t)NQKV_ * D_; // D_*D_
  f16* qb    = wob + (size_t)D_ * D_;      // BHSD
  f16* kb    = qb + BHSD;                  // BHSD
  f16* vtb   = kb + BHSD;                  // BHSD (B,H,hd,S)
  f16* attnb = vtb + BHSD;                 // BHSD
  float2* tab = (float2*)(attnb + BHSD);   // S_*32 float2 = 512 KB
  // total ~92 MB of d_ws

  cast_kernel<<<(M_ * D_) / 2048, 256, 0, stream>>>(x, xb);
  cast_kernel<<<(NQKV_ * D_) / 2048, 256, 0, stream>>>(wqkv, wqkvb);
  cast_kernel<<<(D_ * D_) / 2048, 256, 0, stream>>>(wo, wob);
  trig_kernel<<<(S_ * 32) / 256, 256, 0, stream>>>(pos, tab);

  gemm_bt<0><<<(M_ / 128) * (NQKV_ / 128), 256, 0, stream>>>(
      xb, wqkvb, (void*)qb, tab, kb, vtb, M_, NQKV_, D_);

  attn_kernel<<<64 * 16, 256, 0, stream>>>(qb, kb, vtb, attnb);

  gemm_bt<1><<<(M_ / 128) * (D_ / 128), 256, 0, stream>>>(
      attnb, wob, (void*)out, nullptr, nullptr, nullptr, M_, D_, D_);
}

// Round 8
// 199.786 us; speedup vs baseline: 1.0850x; 1.0362x over previous
//
#include <hip/hip_runtime.h>

#define B_ 4
#define S_ 2048
#define D_ 1024
#define H_ 16
#define HD_ 64
#define M_ (B_*S_)      // 8192 rows
#define NQKV_ (3*D_)    // 3072

typedef _Float16 f16;
typedef __attribute__((ext_vector_type(4))) _Float16 f16x4;
typedef __attribute__((ext_vector_type(8))) _Float16 f16x8;
typedef __attribute__((ext_vector_type(4))) float f32x4;
typedef __attribute__((ext_vector_type(16))) float f32x16;

__device__ __forceinline__ void gload_lds16(const void* g, void* lds) {
  __builtin_amdgcn_global_load_lds(
      (const __attribute__((address_space(1))) void*)g,
      (__attribute__((address_space(3))) void*)lds, 16, 0, 0);
}

// ---------------- cast fp32 -> fp16, 8 elems/thread ----------------
__global__ void cast_kernel(const float* __restrict__ in, f16* __restrict__ out) {
  size_t i = (size_t)(blockIdx.x * 256 + threadIdx.x) * 8;
  float4 a = *reinterpret_cast<const float4*>(in + i);
  float4 b = *reinterpret_cast<const float4*>(in + i + 4);
  f16x8 o;
  o[0] = (f16)a.x; o[1] = (f16)a.y; o[2] = (f16)a.z; o[3] = (f16)a.w;
  o[4] = (f16)b.x; o[5] = (f16)b.y; o[6] = (f16)b.z; o[7] = (f16)b.w;
  *reinterpret_cast<f16x8*>(out + i) = o;
}

// ---------------- RoPE trig table: tab[s][t] = {cos,sin}(pos[s]*invf(t))
__global__ void trig_kernel(const int* __restrict__ pos, float2* __restrict__ tab) {
  int idx = blockIdx.x * 256 + threadIdx.x;   // S_*32 threads
  int s = idx >> 5, t = idx & 31;
  float p = (float)pos[s];
  float invf = exp2f((float)t * -0.4152410118609203f);  // -log2(10000)/32
  float sn, cs;
  sincosf(p * invf, &sn, &cs);
  tab[idx] = float2{cs, sn};
}

// ---------------- GEMM C[m,n] = sum_k A[m,k]*Bt[n,k] ----------------
// Ring-3 counted-vmcnt pipeline (T3/T4-derived, race-free by ledger):
//   iter t: vmcnt(6) -> s_barrier -> STAGE(t+2)->buf[(t+2)%3] -> compute buf[t%3]
// Loads for tiles t+1/t+2 stay in flight across the barrier (no vmcnt(0)
// drain in the loop). BM=128 BN=256 BK=64, 8 waves (2M x 4N), per-wave
// 64x64 output. As/Bs XOR-swizzled (T2, both-sides rule).
// Swapped-operand MFMA: D col=lr -> m, row-regs -> 4 consecutive n.
// MODE 0 (QKV): n/1024 selects Q(rope*qs)/K(rope)/V(transposed write).
// MODE 1: fp32 C row-major, float4 stores.
template <int MODE>
__global__ __launch_bounds__(512)
void gemm_bt(const f16* __restrict__ A, const f16* __restrict__ Bt,
             void* __restrict__ Cout, const float2* __restrict__ tab,
             f16* __restrict__ kout, f16* __restrict__ vtout,
             int M, int N, int K) {
  __shared__ __align__(16) f16 As[3][128 * 64];
  __shared__ __align__(16) f16 Bs[3][256 * 64];
  const int tid = threadIdx.x;
  const int w = tid >> 6, l = tid & 63;
  const int nM = M >> 7;
  const int bm = (blockIdx.x % nM) << 7;
  const int bn = (blockIdx.x / nM) << 8;
  const int wrow = (w >> 2) << 6;   // 0,64
  const int wcol = (w & 3) << 6;    // 0,64,128,192
  const int lr = l & 15;
  const int lk = (l >> 4) << 3;
  const int orow = (l >> 4) << 2;
  const int swz = (lr & 7) << 3;    // read-side XOR

  f32x4 acc[4][4];
  #pragma unroll
  for (int i = 0; i < 4; ++i)
    #pragma unroll
    for (int j = 0; j < 4; ++j) acc[i][j] = f32x4{0.f, 0.f, 0.f, 0.f};

  const int sc8 = (tid & 7) * 8;    // staging col (elems)
  const int NT = K >> 6;            // 16

  // stage K-tile t into ring slot t%3 (pre-swizzled source col)
  #define STAGE(t_) {                                                         \
    const int buf_ = (t_) % 3, k0_ = (t_) << 6;                               \
    _Pragma("unroll")                                                         \
    for (int i = 0; i < 2; ++i) {                                             \
      int row = (i * 512 + tid) >> 3;                                         \
      gload_lds16(A + (size_t)(bm + row) * K + k0_ + (sc8 ^ ((row & 7) << 3)),\
                  (void*)(&As[buf_][(i * 512 + tid) * 8]));                   \
    }                                                                         \
    _Pragma("unroll")                                                         \
    for (int i = 0; i < 4; ++i) {                                             \
      int row = (i * 512 + tid) >> 3;                                         \
      gload_lds16(Bt + (size_t)(bn + row) * K + k0_ + (sc8 ^ ((row & 7) << 3)),\
                  (void*)(&Bs[buf_][(i * 512 + tid) * 8]));                   \
    }                                                                         \
  }

  STAGE(0);
  STAGE(1);

  for (int t = 0; t < NT; ++t) {
    // own tile-t loads are all-but-newest-6 -> landed; then barrier makes
    // that true across all waves AND frees buf[(t+2)%3] (read in iter t-1).
    if (t < NT - 1) {
      asm volatile("s_waitcnt vmcnt(6)" ::: "memory");
    } else {
      asm volatile("s_waitcnt vmcnt(0)" ::: "memory");
    }
    __builtin_amdgcn_sched_barrier(0);
    __builtin_amdgcn_s_barrier();
    __builtin_amdgcn_sched_barrier(0);
    if (t + 2 < NT) STAGE(t + 2);

    const f16* Asc = As[t % 3];
    const f16* Bsc = Bs[t % 3];
    #pragma unroll
    for (int ts = 0; ts < 2; ++ts) {
      f16x8 af[4], bfr[4];
      #pragma unroll
      for (int mi = 0; mi < 4; ++mi)
        af[mi] = *reinterpret_cast<const f16x8*>(
            Asc + (wrow + mi * 16 + lr) * 64 + ((ts * 32 + lk) ^ swz));
      #pragma unroll
      for (int ni = 0; ni < 4; ++ni)
        bfr[ni] = *reinterpret_cast<const f16x8*>(
            Bsc + (wcol + ni * 16 + lr) * 64 + ((ts * 32 + lk) ^ swz));
      #pragma unroll
      for (int mi = 0; mi < 4; ++mi)
        #pragma unroll
        for (int ni = 0; ni < 4; ++ni)
          acc[mi][ni] = __builtin_amdgcn_mfma_f32_16x16x32_f16(bfr[ni], af[mi], acc[mi][ni], 0, 0, 0);
    }
  }
  #undef STAGE

  if (MODE == 0) {
    const int which = bn >> 10;                    // uniform per block
    const int h = ((bn + wcol) >> 6) & (H_ - 1);   // uniform per wave
    if (which < 2) {                               // Q or K: fused RoPE
      f16* dst = which ? kout : (f16*)Cout;
      const float qs = which ? 1.0f : 0.125f * 1.4426950408889634f;  // (1/8)*log2e
      #pragma unroll
      for (int mi = 0; mi < 4; ++mi) {
        int m = bm + wrow + mi * 16 + lr;
        int b = m >> 11, s = m & (S_ - 1);
        size_t rowbase = ((size_t)(b * H_ + h) * S_ + s) * HD_;
        const float4* trow = reinterpret_cast<const float4*>(tab + (size_t)s * 32);
        #pragma unroll
        for (int ni = 0; ni < 4; ++ni) {
          int d0 = ni * 16 + orow;                 // multiple of 4
          float4 cssn = trow[d0 >> 2];
          float x0 = acc[mi][ni][0], x1 = acc[mi][ni][1];
          float x2 = acc[mi][ni][2], x3 = acc[mi][ni][3];
          f16x4 ov;
          ov[0] = (f16)((x0 * cssn.x - x1 * cssn.y) * qs);
          ov[1] = (f16)((x1 * cssn.x + x0 * cssn.y) * qs);
          ov[2] = (f16)((x2 * cssn.z - x3 * cssn.w) * qs);
          ov[3] = (f16)((x3 * cssn.z + x2 * cssn.w) * qs);
          *reinterpret_cast<f16x4*>(&dst[rowbase + d0]) = ov;
        }
      }
    } else {                                       // V: direct transposed write
      #pragma unroll
      for (int mi = 0; mi < 4; ++mi) {
        int m = bm + wrow + mi * 16 + lr;
        int b = m >> 11, s = m & (S_ - 1);
        size_t base = (size_t)(b * H_ + h) * (HD_ * S_) + s;
        #pragma unroll
        for (int ni = 0; ni < 4; ++ni)
          #pragma unroll
          for (int r = 0; r < 4; ++r)
            vtout[base + (size_t)(ni * 16 + orow + r) * S_] = (f16)acc[mi][ni][r];
      }
    }
  } else {
    float* C = (float*)Cout;
    #pragma unroll
    for (int mi = 0; mi < 4; ++mi) {
      int m = bm + wrow + mi * 16 + lr;
      #pragma unroll
      for (int ni = 0; ni < 4; ++ni) {
        int n = bn + wcol + ni * 16 + orow;
        *reinterpret_cast<float4*>(&C[(size_t)m * N + n]) =
            float4{acc[mi][ni][0], acc[mi][ni][1], acc[mi][ni][2], acc[mi][ni][3]};
      }
    }
  }
}

// ---------------- flash attention (causal), 32x32 MFMA form ---------
// (unchanged from Round 7 — passed; est. ~70 us)
__global__ __launch_bounds__(256, 4)
void attn_kernel(const f16* __restrict__ q, const f16* __restrict__ k,
                 const f16* __restrict__ vt, f16* __restrict__ attn_out) {
  __shared__ __align__(16) f16 Ks[64 * 64];
  __shared__ __align__(16) f16 Vs[64 * 64];     // [d][kv]
  __shared__ __align__(16) f16 Ps[4][32 * 64];  // per-wave P[q][kv]
  const int tid = threadIdx.x, wq = tid >> 6, l = tid & 63;
  const int lq = l & 31, hi = l >> 5;
  const int bh = blockIdx.x & 63;
  const int qt = 15 - (int)(blockIdx.x >> 6);   // heavy tiles first
  const int q0 = qt << 7;
  const size_t bhoff = (size_t)bh * (S_ * HD_);
  const size_t vtoff = (size_t)bh * (HD_ * S_);
  const int srow = tid >> 3;
  const int sc8 = (tid & 7) * 8;
  const int ssw = sc8 ^ ((srow & 7) << 3);      // swizzled source col
  const int swz = (lq & 7) << 3;                // read-side XOR
  const int h = bh & (H_ - 1), b = bh >> 4;
  const int wqmin = q0 + wq * 32;
  const int qrow = wqmin + lq;                  // this lane's q-row

  f16x8 qf[4];
  #pragma unroll
  for (int s = 0; s < 4; ++s)
    qf[s] = *reinterpret_cast<const f16x8*>(q + bhoff + (size_t)qrow * HD_ + s * 16 + hi * 8);

  f32x16 o[2];
  float m_run = -1e30f, l_run = 0.f;
  #pragma unroll
  for (int i = 0; i < 2; ++i)
    #pragma unroll
    for (int r = 0; r < 16; ++r) o[i][r] = 0.f;

  f16* Pw = &Ps[wq][0];
  const int ntiles = 2 * qt + 2;
  for (int it = 0; it < ntiles; ++it) {
    const int kv0 = it << 6;
    __syncthreads();
    #pragma unroll
    for (int i = 0; i < 2; ++i) {
      gload_lds16(k + bhoff + (size_t)(kv0 + i * 32 + srow) * HD_ + ssw,
                  (void*)(Ks + (i * 256 + wq * 64) * 8));
      gload_lds16(vt + vtoff + (size_t)(i * 32 + srow) * S_ + kv0 + ssw,
                  (void*)(Vs + (i * 256 + wq * 64) * 8));
    }
    __syncthreads();

    if (kv0 <= wqmin + 31) {   // wave-uniform causal skip
      f32x16 sacc[2];
      #pragma unroll
      for (int kh = 0; kh < 2; ++kh) {
        #pragma unroll
        for (int r = 0; r < 16; ++r) sacc[kh][r] = 0.f;
        #pragma unroll
        for (int s = 0; s < 4; ++s) {
          f16x8 kf = *reinterpret_cast<const f16x8*>(
              Ks + (kh * 32 + lq) * 64 + ((s * 16 + hi * 8) ^ swz));
          sacc[kh] = __builtin_amdgcn_mfma_f32_32x32x16_f16(kf, qf[s], sacc[kh], 0, 0, 0);
        }
      }
      if (kv0 + 63 >= wqmin) {   // diagonal straddle: element mask
        #pragma unroll
        for (int kh = 0; kh < 2; ++kh)
          #pragma unroll
          for (int r = 0; r < 16; ++r) {
            int kvg = kv0 + kh * 32 + (r & 3) + 8 * (r >> 2) + 4 * hi;
            if (kvg > qrow) sacc[kh][r] = -1e30f;
          }
      }

      float mloc = -1e30f;
      #pragma unroll
      for (int kh = 0; kh < 2; ++kh)
        #pragma unroll
        for (int r = 0; r < 16; ++r) mloc = fmaxf(mloc, sacc[kh][r]);
      mloc = fmaxf(mloc, __shfl_xor(mloc, 32));
      float mn = fmaxf(m_run, mloc);
      float scale = exp2f(m_run - mn);
      m_run = mn;
      float sloc = 0.f;
      #pragma unroll
      for (int kh = 0; kh < 2; ++kh)
        #pragma unroll
        for (int r = 0; r < 16; ++r) {
          sacc[kh][r] = exp2f(sacc[kh][r] - mn);
          sloc += sacc[kh][r];
        }
      sloc += __shfl_xor(sloc, 32);
      l_run = l_run * scale + sloc;
      #pragma unroll
      for (int i = 0; i < 2; ++i)
        #pragma unroll
        for (int r = 0; r < 16; ++r) o[i][r] *= scale;

      #pragma unroll
      for (int kh = 0; kh < 2; ++kh)
        #pragma unroll
        for (int qd = 0; qd < 4; ++qd) {
          f16x4 pk;
          #pragma unroll
          for (int r = 0; r < 4; ++r) pk[r] = (f16)sacc[kh][qd * 4 + r];
          int kvb = kh * 32 + qd * 8 + hi * 4;
          *reinterpret_cast<f16x4*>(&Pw[lq * 64 + (kvb ^ swz)]) = pk;
        }

      f16x8 pf[4];
      #pragma unroll
      for (int s2 = 0; s2 < 4; ++s2)
        pf[s2] = *reinterpret_cast<const f16x8*>(&Pw[lq * 64 + ((s2 * 16 + hi * 8) ^ swz)]);
      #pragma unroll
      for (int dh = 0; dh < 2; ++dh)
        #pragma unroll
        for (int s2 = 0; s2 < 4; ++s2) {
          f16x8 vf = *reinterpret_cast<const f16x8*>(
              Vs + (dh * 32 + lq) * 64 + ((s2 * 16 + hi * 8) ^ swz));
          o[dh] = __builtin_amdgcn_mfma_f32_32x32x16_f16(vf, pf[s2], o[dh], 0, 0, 0);
        }
    }
  }

  float rl = 1.0f / l_run;
  #pragma unroll
  for (int dh = 0; dh < 2; ++dh)
    #pragma unroll
    for (int qd = 0; qd < 4; ++qd) {
      f16x4 ov;
      #pragma unroll
      for (int r = 0; r < 4; ++r) ov[r] = (f16)(o[dh][qd * 4 + r] * rl);
      int d0 = dh * 32 + qd * 8 + hi * 4;
      *reinterpret_cast<f16x4*>(
          &attn_out[(size_t)(b * S_ + qrow) * D_ + h * HD_ + d0]) = ov;
    }
}

// ---------------- launch --------------------------------------------
extern "C" void kernel_launch(void* const* d_in, const int* in_sizes, int n_in,
                              void* d_out, int out_size, void* d_ws, size_t ws_size,
                              hipStream_t stream) {
  const float* x    = (const float*)d_in[0];
  const int*   pos  = (const int*)d_in[1];
  const float* wqkv = (const float*)d_in[2];
  const float* wo   = (const float*)d_in[3];
  float* out = (float*)d_out;

  const size_t BHSD = (size_t)B_ * H_ * S_ * HD_;   // 8388608
  f16* xb    = (f16*)d_ws;                 // M_*D_
  f16* wqkvb = xb + (size_t)M_ * D_;       // NQKV_*D_
  f16* wob   = wqkvb + (size_t)NQKV_ * D_; // D_*D_
  f16* qb    = wob + (size_t)D_ * D_;      // BHSD
  f16* kb    = qb + BHSD;                  // BHSD
  f16* vtb   = kb + BHSD;                  // BHSD (B,H,hd,S)
  f16* attnb = vtb + BHSD;                 // BHSD
  float2* tab = (float2*)(attnb + BHSD);   // S_*32 float2 = 512 KB
  // total ~92 MB of d_ws

  cast_kernel<<<(M_ * D_) / 2048, 256, 0, stream>>>(x, xb);
  cast_kernel<<<(NQKV_ * D_) / 2048, 256, 0, stream>>>(wqkv, wqkvb);
  cast_kernel<<<(D_ * D_) / 2048, 256, 0, stream>>>(wo, wob);
  trig_kernel<<<(S_ * 32) / 256, 256, 0, stream>>>(pos, tab);

  gemm_bt<0><<<(M_ / 128) * (NQKV_ / 256), 512, 0, stream>>>(
      xb, wqkvb, (void*)qb, tab, kb, vtb, M_, NQKV_, D_);

  attn_kernel<<<64 * 16, 256, 0, stream>>>(qb, kb, vtb, attnb);

  gemm_bt<1><<<(M_ / 128) * (D_ / 256), 512, 0, stream>>>(
      attnb, wob, (void*)out, nullptr, nullptr, nullptr, M_, D_, D_);
}

// Round 9
// 194.981 us; speedup vs baseline: 1.1118x; 1.0246x over previous
//
#include <hip/hip_runtime.h>

#define B_ 4
#define S_ 2048
#define D_ 1024
#define H_ 16
#define HD_ 64
#define M_ (B_*S_)      // 8192 rows
#define NQKV_ (3*D_)    // 3072

typedef _Float16 f16;
typedef __attribute__((ext_vector_type(4))) _Float16 f16x4;
typedef __attribute__((ext_vector_type(8))) _Float16 f16x8;
typedef __attribute__((ext_vector_type(4))) float f32x4;
typedef __attribute__((ext_vector_type(16))) float f32x16;

__device__ __forceinline__ void gload_lds16(const void* g, void* lds) {
  __builtin_amdgcn_global_load_lds(
      (const __attribute__((address_space(1))) void*)g,
      (__attribute__((address_space(3))) void*)lds, 16, 0, 0);
}

// ---------------- cast fp32 -> fp16, 8 elems/thread ----------------
__global__ void cast_kernel(const float* __restrict__ in, f16* __restrict__ out) {
  size_t i = (size_t)(blockIdx.x * 256 + threadIdx.x) * 8;
  float4 a = *reinterpret_cast<const float4*>(in + i);
  float4 b = *reinterpret_cast<const float4*>(in + i + 4);
  f16x8 o;
  o[0] = (f16)a.x; o[1] = (f16)a.y; o[2] = (f16)a.z; o[3] = (f16)a.w;
  o[4] = (f16)b.x; o[5] = (f16)b.y; o[6] = (f16)b.z; o[7] = (f16)b.w;
  *reinterpret_cast<f16x8*>(out + i) = o;
}

// ---------------- RoPE trig table: tab[s][t] = {cos,sin}(pos[s]*invf(t))
__global__ void trig_kernel(const int* __restrict__ pos, float2* __restrict__ tab) {
  int idx = blockIdx.x * 256 + threadIdx.x;   // S_*32 threads
  int s = idx >> 5, t = idx & 31;
  float p = (float)pos[s];
  float invf = exp2f((float)t * -0.4152410118609203f);  // -log2(10000)/32
  float sn, cs;
  sincosf(p * invf, &sn, &cs);
  tab[idx] = float2{cs, sn};
}

// ---------------- GEMM C[m,n] = sum_k A[m,k]*Bt[n,k] ----------------
// Minimum-2-phase ring-2 (T3 catalog recipe):
//   prologue STAGE(0); barrier;
//   iter t: STAGE(t+1) -> buf[(t+1)&1]; compute buf[t&1]; __syncthreads()
// Ledger: buf[(t+1)&1] last read at compute(t-1), protected by end-of-(t-1)
// barrier; tile-t loads drained by end-of-(t-1) barrier's vmcnt(0), whose
// latency hid under compute(t-1).
// BM=256, 8 waves as 4M x 2N; per-wave 64 x (NB*32) in 32x32x16 MFMAs.
// MODE 0: NB=3 (BN=192), epilogue routes per 8-col group to Q(rope*qs)/
//         K(rope)/V(transposed) since BN straddles the 1024-boundaries.
// MODE 1: NB=2 (BN=128), fp32 C row-major float4 stores.
// As/Bs XOR-swizzled (T2 both-sides: pre-swizzled gload src + swz ds_read).
// Swapped-operand MFMA: D col(lane&31)->m, row-regs->n (verified by attn).
template <int MODE>
__global__ __launch_bounds__(512, 2)
void gemm_bt(const f16* __restrict__ A, const f16* __restrict__ Bt,
             void* __restrict__ Cout, const float2* __restrict__ tab,
             f16* __restrict__ kout, f16* __restrict__ vtout,
             int M, int N, int K) {
  constexpr int NB = (MODE == 0) ? 3 : 2;   // 32-col blocks per wave
  constexpr int BN = NB * 64;               // 192 / 128
  constexpr int BP = BN / 64;               // B staging passes
  __shared__ __align__(16) f16 As[2][256 * 64];
  __shared__ __align__(16) f16 Bs[2][BN * 64];
  const int tid = threadIdx.x;
  const int w = tid >> 6, l = tid & 63;
  const int lq = l & 31, hi = l >> 5;
  const int nM = M >> 8;
  const int bm = (int)(blockIdx.x % nM) << 8;
  const int bn = (int)(blockIdx.x / nM) * BN;
  const int wrow = (w >> 1) << 6;           // 0,64,128,192
  const int wcol = (w & 1) * (NB * 32);     // 0 / NB*32
  const int swz = (lq & 7) << 3;            // read-side XOR (elems)
  const int srow = tid >> 3;                // staging row (8 thr/row)
  const int ssw = ((tid & 7) * 8) ^ ((srow & 7) << 3);  // swizzled src col
  const int NT = K >> 6;                    // 16

  f32x16 acc[2][NB];
  #pragma unroll
  for (int i = 0; i < 2; ++i)
    #pragma unroll
    for (int j = 0; j < NB; ++j)
      #pragma unroll
      for (int r = 0; r < 16; ++r) acc[i][j][r] = 0.f;

#define STAGE(t_) do {                                                   \
    const int buf_ = (t_) & 1; const int k0_ = (t_) << 6;                \
    _Pragma("unroll")                                                    \
    for (int i = 0; i < 4; ++i)                                          \
      gload_lds16(A + (size_t)(bm + i * 64 + srow) * K + k0_ + ssw,      \
                  (void*)(&As[buf_][(i * 512 + tid) * 8]));              \
    _Pragma("unroll")                                                    \
    for (int i = 0; i < BP; ++i)                                         \
      gload_lds16(Bt + (size_t)(bn + i * 64 + srow) * K + k0_ + ssw,     \
                  (void*)(&Bs[buf_][(i * 512 + tid) * 8]));              \
  } while (0)

  STAGE(0);
  __syncthreads();

  for (int t = 0; t < NT; ++t) {
    if (t + 1 < NT) STAGE(t + 1);
    const f16* Asc = As[t & 1];
    const f16* Bsc = Bs[t & 1];
    #pragma unroll
    for (int ks = 0; ks < 4; ++ks) {
      f16x8 af[2], bf[NB];
      #pragma unroll
      for (int mi = 0; mi < 2; ++mi)
        af[mi] = *reinterpret_cast<const f16x8*>(
            Asc + (wrow + mi * 32 + lq) * 64 + ((ks * 16 + hi * 8) ^ swz));
      #pragma unroll
      for (int ni = 0; ni < NB; ++ni)
        bf[ni] = *reinterpret_cast<const f16x8*>(
            Bsc + (wcol + ni * 32 + lq) * 64 + ((ks * 16 + hi * 8) ^ swz));
      #pragma unroll
      for (int mi = 0; mi < 2; ++mi)
        #pragma unroll
        for (int ni = 0; ni < NB; ++ni)
          acc[mi][ni] = __builtin_amdgcn_mfma_f32_32x32x16_f16(bf[ni], af[mi], acc[mi][ni], 0, 0, 0);
    }
    __syncthreads();
  }
#undef STAGE

  if (MODE == 0) {
    const float QS = 0.125f * 1.4426950408889634f;   // (1/8)*log2e
    #pragma unroll
    for (int mi = 0; mi < 2; ++mi) {
      int m = bm + wrow + mi * 32 + lq;
      int b = m >> 11, s = m & (S_ - 1);
      const float4* trow = reinterpret_cast<const float4*>(tab + (size_t)s * 32);
      #pragma unroll
      for (int ni = 0; ni < NB; ++ni) {
        #pragma unroll
        for (int g = 0; g < 4; ++g) {
          int n = bn + wcol + ni * 32 + g * 8 + hi * 4;   // 8-aligned group base+hi*4
          int which = n >> 10, h = (n >> 6) & (H_ - 1), d = n & 63;
          float x0 = acc[mi][ni][g * 4 + 0], x1 = acc[mi][ni][g * 4 + 1];
          float x2 = acc[mi][ni][g * 4 + 2], x3 = acc[mi][ni][g * 4 + 3];
          if (which < 2) {                   // Q or K: fused RoPE
            float4 cs = trow[d >> 2];
            float qs = which ? 1.0f : QS;
            f16x4 ov;
            ov[0] = (f16)((x0 * cs.x - x1 * cs.y) * qs);
            ov[1] = (f16)((x1 * cs.x + x0 * cs.y) * qs);
            ov[2] = (f16)((x2 * cs.z - x3 * cs.w) * qs);
            ov[3] = (f16)((x3 * cs.z + x2 * cs.w) * qs);
            f16* dst = which ? kout : (f16*)Cout;
            *reinterpret_cast<f16x4*>(
                &dst[((size_t)(b * H_ + h) * S_ + s) * HD_ + d]) = ov;
          } else {                           // V: transposed write
            size_t base = (size_t)(b * H_ + h) * (HD_ * S_) + s;
            vtout[base + (size_t)(d + 0) * S_] = (f16)x0;
            vtout[base + (size_t)(d + 1) * S_] = (f16)x1;
            vtout[base + (size_t)(d + 2) * S_] = (f16)x2;
            vtout[base + (size_t)(d + 3) * S_] = (f16)x3;
          }
        }
      }
    }
  } else {
    float* C = (float*)Cout;
    #pragma unroll
    for (int mi = 0; mi < 2; ++mi) {
      int m = bm + wrow + mi * 32 + lq;
      #pragma unroll
      for (int ni = 0; ni < NB; ++ni)
        #pragma unroll
        for (int g = 0; g < 4; ++g) {
          int n = bn + wcol + ni * 32 + g * 8 + hi * 4;
          *reinterpret_cast<float4*>(&C[(size_t)m * N + n]) =
              float4{acc[mi][ni][g * 4 + 0], acc[mi][ni][g * 4 + 1],
                     acc[mi][ni][g * 4 + 2], acc[mi][ni][g * 4 + 3]};
        }
    }
  }
}

// ---------------- flash attention (causal), 32x32 MFMA form ---------
// (unchanged — passed, ~70 us)
__global__ __launch_bounds__(256, 4)
void attn_kernel(const f16* __restrict__ q, const f16* __restrict__ k,
                 const f16* __restrict__ vt, f16* __restrict__ attn_out) {
  __shared__ __align__(16) f16 Ks[64 * 64];
  __shared__ __align__(16) f16 Vs[64 * 64];     // [d][kv]
  __shared__ __align__(16) f16 Ps[4][32 * 64];  // per-wave P[q][kv]
  const int tid = threadIdx.x, wq = tid >> 6, l = tid & 63;
  const int lq = l & 31, hi = l >> 5;
  const int bh = blockIdx.x & 63;
  const int qt = 15 - (int)(blockIdx.x >> 6);   // heavy tiles first
  const int q0 = qt << 7;
  const size_t bhoff = (size_t)bh * (S_ * HD_);
  const size_t vtoff = (size_t)bh * (HD_ * S_);
  const int srow = tid >> 3;
  const int sc8 = (tid & 7) * 8;
  const int ssw = sc8 ^ ((srow & 7) << 3);      // swizzled source col
  const int swz = (lq & 7) << 3;                // read-side XOR
  const int h = bh & (H_ - 1), b = bh >> 4;
  const int wqmin = q0 + wq * 32;
  const int qrow = wqmin + lq;                  // this lane's q-row

  f16x8 qf[4];
  #pragma unroll
  for (int s = 0; s < 4; ++s)
    qf[s] = *reinterpret_cast<const f16x8*>(q + bhoff + (size_t)qrow * HD_ + s * 16 + hi * 8);

  f32x16 o[2];
  float m_run = -1e30f, l_run = 0.f;
  #pragma unroll
  for (int i = 0; i < 2; ++i)
    #pragma unroll
    for (int r = 0; r < 16; ++r) o[i][r] = 0.f;

  f16* Pw = &Ps[wq][0];
  const int ntiles = 2 * qt + 2;
  for (int it = 0; it < ntiles; ++it) {
    const int kv0 = it << 6;
    __syncthreads();
    #pragma unroll
    for (int i = 0; i < 2; ++i) {
      gload_lds16(k + bhoff + (size_t)(kv0 + i * 32 + srow) * HD_ + ssw,
                  (void*)(Ks + (i * 256 + wq * 64) * 8));
      gload_lds16(vt + vtoff + (size_t)(i * 32 + srow) * S_ + kv0 + ssw,
                  (void*)(Vs + (i * 256 + wq * 64) * 8));
    }
    __syncthreads();

    if (kv0 <= wqmin + 31) {   // wave-uniform causal skip
      f32x16 sacc[2];
      #pragma unroll
      for (int kh = 0; kh < 2; ++kh) {
        #pragma unroll
        for (int r = 0; r < 16; ++r) sacc[kh][r] = 0.f;
        #pragma unroll
        for (int s = 0; s < 4; ++s) {
          f16x8 kf = *reinterpret_cast<const f16x8*>(
              Ks + (kh * 32 + lq) * 64 + ((s * 16 + hi * 8) ^ swz));
          sacc[kh] = __builtin_amdgcn_mfma_f32_32x32x16_f16(kf, qf[s], sacc[kh], 0, 0, 0);
        }
      }
      if (kv0 + 63 >= wqmin) {   // diagonal straddle: element mask
        #pragma unroll
        for (int kh = 0; kh < 2; ++kh)
          #pragma unroll
          for (int r = 0; r < 16; ++r) {
            int kvg = kv0 + kh * 32 + (r & 3) + 8 * (r >> 2) + 4 * hi;
            if (kvg > qrow) sacc[kh][r] = -1e30f;
          }
      }

      float mloc = -1e30f;
      #pragma unroll
      for (int kh = 0; kh < 2; ++kh)
        #pragma unroll
        for (int r = 0; r < 16; ++r) mloc = fmaxf(mloc, sacc[kh][r]);
      mloc = fmaxf(mloc, __shfl_xor(mloc, 32));
      float mn = fmaxf(m_run, mloc);
      float scale = exp2f(m_run - mn);
      m_run = mn;
      float sloc = 0.f;
      #pragma unroll
      for (int kh = 0; kh < 2; ++kh)
        #pragma unroll
        for (int r = 0; r < 16; ++r) {
          sacc[kh][r] = exp2f(sacc[kh][r] - mn);
          sloc += sacc[kh][r];
        }
      sloc += __shfl_xor(sloc, 32);
      l_run = l_run * scale + sloc;
      #pragma unroll
      for (int i = 0; i < 2; ++i)
        #pragma unroll
        for (int r = 0; r < 16; ++r) o[i][r] *= scale;

      #pragma unroll
      for (int kh = 0; kh < 2; ++kh)
        #pragma unroll
        for (int qd = 0; qd < 4; ++qd) {
          f16x4 pk;
          #pragma unroll
          for (int r = 0; r < 4; ++r) pk[r] = (f16)sacc[kh][qd * 4 + r];
          int kvb = kh * 32 + qd * 8 + hi * 4;
          *reinterpret_cast<f16x4*>(&Pw[lq * 64 + (kvb ^ swz)]) = pk;
        }

      f16x8 pf[4];
      #pragma unroll
      for (int s2 = 0; s2 < 4; ++s2)
        pf[s2] = *reinterpret_cast<const f16x8*>(&Pw[lq * 64 + ((s2 * 16 + hi * 8) ^ swz)]);
      #pragma unroll
      for (int dh = 0; dh < 2; ++dh)
        #pragma unroll
        for (int s2 = 0; s2 < 4; ++s2) {
          f16x8 vf = *reinterpret_cast<const f16x8*>(
              Vs + (dh * 32 + lq) * 64 + ((s2 * 16 + hi * 8) ^ swz));
          o[dh] = __builtin_amdgcn_mfma_f32_32x32x16_f16(vf, pf[s2], o[dh], 0, 0, 0);
        }
    }
  }

  float rl = 1.0f / l_run;
  #pragma unroll
  for (int dh = 0; dh < 2; ++dh)
    #pragma unroll
    for (int qd = 0; qd < 4; ++qd) {
      f16x4 ov;
      #pragma unroll
      for (int r = 0; r < 4; ++r) ov[r] = (f16)(o[dh][qd * 4 + r] * rl);
      int d0 = dh * 32 + qd * 8 + hi * 4;
      *reinterpret_cast<f16x4*>(
          &attn_out[(size_t)(b * S_ + qrow) * D_ + h * HD_ + d0]) = ov;
    }
}

// ---------------- launch --------------------------------------------
extern "C" void kernel_launch(void* const* d_in, const int* in_sizes, int n_in,
                              void* d_out, int out_size, void* d_ws, size_t ws_size,
                              hipStream_t stream) {
  const float* x    = (const float*)d_in[0];
  const int*   pos  = (const int*)d_in[1];
  const float* wqkv = (const float*)d_in[2];
  const float* wo   = (const float*)d_in[3];
  float* out = (float*)d_out;

  const size_t BHSD = (size_t)B_ * H_ * S_ * HD_;   // 8388608
  f16* xb    = (f16*)d_ws;                 // M_*D_
  f16* wqkvb = xb + (size_t)M_ * D_;       // NQKV_*D_
  f16* wob   = wqkvb + (size_t)NQKV_ * D_; // D_*D_
  f16* qb    = wob + (size_t)D_ * D_;      // BHSD
  f16* kb    = qb + BHSD;                  // BHSD
  f16* vtb   = kb + BHSD;                  // BHSD (B,H,hd,S)
  f16* attnb = vtb + BHSD;                 // BHSD
  float2* tab = (float2*)(attnb + BHSD);   // S_*32 float2 = 512 KB
  // total ~92 MB of d_ws

  cast_kernel<<<(M_ * D_) / 2048, 256, 0, stream>>>(x, xb);
  cast_kernel<<<(NQKV_ * D_) / 2048, 256, 0, stream>>>(wqkv, wqkvb);
  cast_kernel<<<(D_ * D_) / 2048, 256, 0, stream>>>(wo, wob);
  trig_kernel<<<(S_ * 32) / 256, 256, 0, stream>>>(pos, tab);

  gemm_bt<0><<<(M_ / 256) * (NQKV_ / 192), 512, 0, stream>>>(
      xb, wqkvb, (void*)qb, tab, kb, vtb, M_, NQKV_, D_);

  attn_kernel<<<64 * 16, 256, 0, stream>>>(qb, kb, vtb, attnb);

  gemm_bt<1><<<(M_ / 256) * (D_ / 128), 512, 0, stream>>>(
      attnb, wob, (void*)out, nullptr, nullptr, nullptr, M_, D_, D_);
}

// Round 10
// 191.638 us; speedup vs baseline: 1.1312x; 1.0174x over previous
//
#include <hip/hip_runtime.h>

#define B_ 4
#define S_ 2048
#define D_ 1024
#define H_ 16
#define HD_ 64
#define M_ (B_*S_)      // 8192 rows
#define NQKV_ (3*D_)    // 3072

typedef _Float16 f16;
typedef __attribute__((ext_vector_type(4))) _Float16 f16x4;
typedef __attribute__((ext_vector_type(8))) _Float16 f16x8;
typedef __attribute__((ext_vector_type(4))) float f32x4;
typedef __attribute__((ext_vector_type(16))) float f32x16;

__device__ __forceinline__ void gload_lds16(const void* g, void* lds) {
  __builtin_amdgcn_global_load_lds(
      (const __attribute__((address_space(1))) void*)g,
      (__attribute__((address_space(3))) void*)lds, 16, 0, 0);
}

// ---------------- cast fp32 -> fp16, 8 elems/thread ----------------
__global__ void cast_kernel(const float* __restrict__ in, f16* __restrict__ out) {
  size_t i = (size_t)(blockIdx.x * 256 + threadIdx.x) * 8;
  float4 a = *reinterpret_cast<const float4*>(in + i);
  float4 b = *reinterpret_cast<const float4*>(in + i + 4);
  f16x8 o;
  o[0] = (f16)a.x; o[1] = (f16)a.y; o[2] = (f16)a.z; o[3] = (f16)a.w;
  o[4] = (f16)b.x; o[5] = (f16)b.y; o[6] = (f16)b.z; o[7] = (f16)b.w;
  *reinterpret_cast<f16x8*>(out + i) = o;
}

// ---------------- RoPE trig table: tab[s][t] = {cos,sin}(pos[s]*invf(t))
__global__ void trig_kernel(const int* __restrict__ pos, float2* __restrict__ tab) {
  int idx = blockIdx.x * 256 + threadIdx.x;   // S_*32 threads
  int s = idx >> 5, t = idx & 31;
  float p = (float)pos[s];
  float invf = exp2f((float)t * -0.4152410118609203f);  // -log2(10000)/32
  float sn, cs;
  sincosf(p * invf, &sn, &cs);
  tab[idx] = float2{cs, sn};
}

// ---------------- GEMM C[m,n] = sum_k A[m,k]*Bt[n,k] ----------------
// Residency-first counted-vmcnt ring-2:
//   128x128 tile, BK=32, 4 waves, LDS 32 KB -> 4 blocks/CU (16 waves).
//   iter t: STAGE(t+1); vmcnt(4) [tile-t landed, t+1 in flight];
//           s_barrier; compute buf[t&1]; s_barrier [frees buf for t+2].
// No vmcnt(0) drain in the loop; load latency spans a full compute
// phase; 4 co-resident blocks fill barrier/latency gaps.
// Fragments: proven 0-conflict 16-row pattern (lr=l&15, lk quarter
// spread); XOR swizzle f(row)=(row&3)<<3 elems (64B rows), both sides.
// Swapped-operand MFMA: D col=lr -> m, row-regs -> 4 consecutive n.
// MODE 0 (QKV): n/1024 routes Q(rope*qs)/K(rope)/V(transposed write).
// MODE 1: fp32 C row-major, float4 stores.
template <int MODE>
__global__ __launch_bounds__(256, 4)
void gemm_bt(const f16* __restrict__ A, const f16* __restrict__ Bt,
             void* __restrict__ Cout, const float2* __restrict__ tab,
             f16* __restrict__ kout, f16* __restrict__ vtout,
             int M, int N, int K) {
  __shared__ __align__(16) f16 As[2][128 * 32];
  __shared__ __align__(16) f16 Bs[2][128 * 32];
  const int tid = threadIdx.x;
  const int w = tid >> 6, l = tid & 63;
  const int nM = M >> 7;
  const int bm = (int)(blockIdx.x % nM) << 7;
  const int bn = (int)(blockIdx.x / nM) << 7;
  const int wrow = (w >> 1) << 6;   // 0,64
  const int wcol = (w & 1) << 6;    // 0,64
  const int lr = l & 15;
  const int lk = (l >> 4) << 3;     // 0,8,16,24
  const int orow = (l >> 4) << 2;
  const int swzr = (lr & 3) << 3;   // read-side XOR (elems), 64B rows
  const int NT = K >> 5;            // 32

  f32x4 acc[4][4];
  #pragma unroll
  for (int i = 0; i < 4; ++i)
    #pragma unroll
    for (int j = 0; j < 4; ++j) acc[i][j] = f32x4{0.f, 0.f, 0.f, 0.f};

  // staging: 4 threads/row, 16B each; source col pre-swizzled
  const int srow4 = tid >> 2;            // row within 64-row pass
  const int ssw = ((tid & 3) * 8) ^ ((srow4 & 3) << 3);

#define STAGE(t_) do {                                                    \
    const int buf_ = (t_) & 1; const int k0_ = (t_) << 5;                 \
    _Pragma("unroll")                                                     \
    for (int p = 0; p < 2; ++p)                                           \
      gload_lds16(A + (size_t)(bm + p * 64 + srow4) * K + k0_ + ssw,      \
                  (void*)(&As[buf_][(p * 256 + tid) * 8]));               \
    _Pragma("unroll")                                                     \
    for (int p = 0; p < 2; ++p)                                           \
      gload_lds16(Bt + (size_t)(bn + p * 64 + srow4) * K + k0_ + ssw,     \
                  (void*)(&Bs[buf_][(p * 256 + tid) * 8]));               \
  } while (0)

  STAGE(0);

  for (int t = 0; t < NT; ++t) {
    if (t + 1 < NT) {
      STAGE(t + 1);
      asm volatile("s_waitcnt vmcnt(4)" ::: "memory");   // tile t landed
    } else {
      asm volatile("s_waitcnt vmcnt(0)" ::: "memory");
    }
    __builtin_amdgcn_sched_barrier(0);
    __builtin_amdgcn_s_barrier();       // tile t visible to all waves
    __builtin_amdgcn_sched_barrier(0);

    const f16* Asc = As[t & 1];
    const f16* Bsc = Bs[t & 1];
    f16x8 af[4], bf[4];
    #pragma unroll
    for (int mi = 0; mi < 4; ++mi)
      af[mi] = *reinterpret_cast<const f16x8*>(
          Asc + (wrow + mi * 16 + lr) * 32 + (lk ^ swzr));
    #pragma unroll
    for (int ni = 0; ni < 4; ++ni)
      bf[ni] = *reinterpret_cast<const f16x8*>(
          Bsc + (wcol + ni * 16 + lr) * 32 + (lk ^ swzr));
    #pragma unroll
    for (int mi = 0; mi < 4; ++mi)
      #pragma unroll
      for (int ni = 0; ni < 4; ++ni)
        acc[mi][ni] = __builtin_amdgcn_mfma_f32_16x16x32_f16(bf[ni], af[mi], acc[mi][ni], 0, 0, 0);

    __builtin_amdgcn_sched_barrier(0);
    __builtin_amdgcn_s_barrier();       // all reads of buf[t&1] done
    __builtin_amdgcn_sched_barrier(0);
  }
#undef STAGE

  if (MODE == 0) {
    const int which = bn >> 10;                    // uniform per block
    const int h = ((bn + wcol) >> 6) & (H_ - 1);   // uniform per wave
    if (which < 2) {                               // Q or K: fused RoPE
      f16* dst = which ? kout : (f16*)Cout;
      const float qs = which ? 1.0f : 0.125f * 1.4426950408889634f;  // (1/8)*log2e
      #pragma unroll
      for (int mi = 0; mi < 4; ++mi) {
        int m = bm + wrow + mi * 16 + lr;
        int b = m >> 11, s = m & (S_ - 1);
        size_t rowbase = ((size_t)(b * H_ + h) * S_ + s) * HD_;
        const float4* trow = reinterpret_cast<const float4*>(tab + (size_t)s * 32);
        #pragma unroll
        for (int ni = 0; ni < 4; ++ni) {
          int d0 = ni * 16 + orow;                 // multiple of 4
          float4 cssn = trow[d0 >> 2];
          float x0 = acc[mi][ni][0], x1 = acc[mi][ni][1];
          float x2 = acc[mi][ni][2], x3 = acc[mi][ni][3];
          f16x4 ov;
          ov[0] = (f16)((x0 * cssn.x - x1 * cssn.y) * qs);
          ov[1] = (f16)((x1 * cssn.x + x0 * cssn.y) * qs);
          ov[2] = (f16)((x2 * cssn.z - x3 * cssn.w) * qs);
          ov[3] = (f16)((x3 * cssn.z + x2 * cssn.w) * qs);
          *reinterpret_cast<f16x4*>(&dst[rowbase + d0]) = ov;
        }
      }
    } else {                                       // V: direct transposed write
      #pragma unroll
      for (int mi = 0; mi < 4; ++mi) {
        int m = bm + wrow + mi * 16 + lr;
        int b = m >> 11, s = m & (S_ - 1);
        size_t base = (size_t)(b * H_ + h) * (HD_ * S_) + s;
        #pragma unroll
        for (int ni = 0; ni < 4; ++ni)
          #pragma unroll
          for (int r = 0; r < 4; ++r)
            vtout[base + (size_t)(ni * 16 + orow + r) * S_] = (f16)acc[mi][ni][r];
      }
    }
  } else {
    float* C = (float*)Cout;
    #pragma unroll
    for (int mi = 0; mi < 4; ++mi) {
      int m = bm + wrow + mi * 16 + lr;
      #pragma unroll
      for (int ni = 0; ni < 4; ++ni) {
        int n = bn + wcol + ni * 16 + orow;
        *reinterpret_cast<float4*>(&C[(size_t)m * N + n]) =
            float4{acc[mi][ni][0], acc[mi][ni][1], acc[mi][ni][2], acc[mi][ni][3]};
      }
    }
  }
}

// ---------------- flash attention (causal), 32x32 MFMA form ---------
// (unchanged — passed, ~70 us)
__global__ __launch_bounds__(256, 4)
void attn_kernel(const f16* __restrict__ q, const f16* __restrict__ k,
                 const f16* __restrict__ vt, f16* __restrict__ attn_out) {
  __shared__ __align__(16) f16 Ks[64 * 64];
  __shared__ __align__(16) f16 Vs[64 * 64];     // [d][kv]
  __shared__ __align__(16) f16 Ps[4][32 * 64];  // per-wave P[q][kv]
  const int tid = threadIdx.x, wq = tid >> 6, l = tid & 63;
  const int lq = l & 31, hi = l >> 5;
  const int bh = blockIdx.x & 63;
  const int qt = 15 - (int)(blockIdx.x >> 6);   // heavy tiles first
  const int q0 = qt << 7;
  const size_t bhoff = (size_t)bh * (S_ * HD_);
  const size_t vtoff = (size_t)bh * (HD_ * S_);
  const int srow = tid >> 3;
  const int sc8 = (tid & 7) * 8;
  const int ssw = sc8 ^ ((srow & 7) << 3);      // swizzled source col
  const int swz = (lq & 7) << 3;                // read-side XOR
  const int h = bh & (H_ - 1), b = bh >> 4;
  const int wqmin = q0 + wq * 32;
  const int qrow = wqmin + lq;                  // this lane's q-row

  f16x8 qf[4];
  #pragma unroll
  for (int s = 0; s < 4; ++s)
    qf[s] = *reinterpret_cast<const f16x8*>(q + bhoff + (size_t)qrow * HD_ + s * 16 + hi * 8);

  f32x16 o[2];
  float m_run = -1e30f, l_run = 0.f;
  #pragma unroll
  for (int i = 0; i < 2; ++i)
    #pragma unroll
    for (int r = 0; r < 16; ++r) o[i][r] = 0.f;

  f16* Pw = &Ps[wq][0];
  const int ntiles = 2 * qt + 2;
  for (int it = 0; it < ntiles; ++it) {
    const int kv0 = it << 6;
    __syncthreads();
    #pragma unroll
    for (int i = 0; i < 2; ++i) {
      gload_lds16(k + bhoff + (size_t)(kv0 + i * 32 + srow) * HD_ + ssw,
                  (void*)(Ks + (i * 256 + wq * 64) * 8));
      gload_lds16(vt + vtoff + (size_t)(i * 32 + srow) * S_ + kv0 + ssw,
                  (void*)(Vs + (i * 256 + wq * 64) * 8));
    }
    __syncthreads();

    if (kv0 <= wqmin + 31) {   // wave-uniform causal skip
      f32x16 sacc[2];
      #pragma unroll
      for (int kh = 0; kh < 2; ++kh) {
        #pragma unroll
        for (int r = 0; r < 16; ++r) sacc[kh][r] = 0.f;
        #pragma unroll
        for (int s = 0; s < 4; ++s) {
          f16x8 kf = *reinterpret_cast<const f16x8*>(
              Ks + (kh * 32 + lq) * 64 + ((s * 16 + hi * 8) ^ swz));
          sacc[kh] = __builtin_amdgcn_mfma_f32_32x32x16_f16(kf, qf[s], sacc[kh], 0, 0, 0);
        }
      }
      if (kv0 + 63 >= wqmin) {   // diagonal straddle: element mask
        #pragma unroll
        for (int kh = 0; kh < 2; ++kh)
          #pragma unroll
          for (int r = 0; r < 16; ++r) {
            int kvg = kv0 + kh * 32 + (r & 3) + 8 * (r >> 2) + 4 * hi;
            if (kvg > qrow) sacc[kh][r] = -1e30f;
          }
      }

      float mloc = -1e30f;
      #pragma unroll
      for (int kh = 0; kh < 2; ++kh)
        #pragma unroll
        for (int r = 0; r < 16; ++r) mloc = fmaxf(mloc, sacc[kh][r]);
      mloc = fmaxf(mloc, __shfl_xor(mloc, 32));
      float mn = fmaxf(m_run, mloc);
      float scale = exp2f(m_run - mn);
      m_run = mn;
      float sloc = 0.f;
      #pragma unroll
      for (int kh = 0; kh < 2; ++kh)
        #pragma unroll
        for (int r = 0; r < 16; ++r) {
          sacc[kh][r] = exp2f(sacc[kh][r] - mn);
          sloc += sacc[kh][r];
        }
      sloc += __shfl_xor(sloc, 32);
      l_run = l_run * scale + sloc;
      #pragma unroll
      for (int i = 0; i < 2; ++i)
        #pragma unroll
        for (int r = 0; r < 16; ++r) o[i][r] *= scale;

      #pragma unroll
      for (int kh = 0; kh < 2; ++kh)
        #pragma unroll
        for (int qd = 0; qd < 4; ++qd) {
          f16x4 pk;
          #pragma unroll
          for (int r = 0; r < 4; ++r) pk[r] = (f16)sacc[kh][qd * 4 + r];
          int kvb = kh * 32 + qd * 8 + hi * 4;
          *reinterpret_cast<f16x4*>(&Pw[lq * 64 + (kvb ^ swz)]) = pk;
        }

      f16x8 pf[4];
      #pragma unroll
      for (int s2 = 0; s2 < 4; ++s2)
        pf[s2] = *reinterpret_cast<const f16x8*>(&Pw[lq * 64 + ((s2 * 16 + hi * 8) ^ swz)]);
      #pragma unroll
      for (int dh = 0; dh < 2; ++dh)
        #pragma unroll
        for (int s2 = 0; s2 < 4; ++s2) {
          f16x8 vf = *reinterpret_cast<const f16x8*>(
              Vs + (dh * 32 + lq) * 64 + ((s2 * 16 + hi * 8) ^ swz));
          o[dh] = __builtin_amdgcn_mfma_f32_32x32x16_f16(vf, pf[s2], o[dh], 0, 0, 0);
        }
    }
  }

  float rl = 1.0f / l_run;
  #pragma unroll
  for (int dh = 0; dh < 2; ++dh)
    #pragma unroll
    for (int qd = 0; qd < 4; ++qd) {
      f16x4 ov;
      #pragma unroll
      for (int r = 0; r < 4; ++r) ov[r] = (f16)(o[dh][qd * 4 + r] * rl);
      int d0 = dh * 32 + qd * 8 + hi * 4;
      *reinterpret_cast<f16x4*>(
          &attn_out[(size_t)(b * S_ + qrow) * D_ + h * HD_ + d0]) = ov;
    }
}

// ---------------- launch --------------------------------------------
extern "C" void kernel_launch(void* const* d_in, const int* in_sizes, int n_in,
                              void* d_out, int out_size, void* d_ws, size_t ws_size,
                              hipStream_t stream) {
  const float* x    = (const float*)d_in[0];
  const int*   pos  = (const int*)d_in[1];
  const float* wqkv = (const float*)d_in[2];
  const float* wo   = (const float*)d_in[3];
  float* out = (float*)d_out;

  const size_t BHSD = (size_t)B_ * H_ * S_ * HD_;   // 8388608
  f16* xb    = (f16*)d_ws;                 // M_*D_
  f16* wqkvb = xb + (size_t)M_ * D_;       // NQKV_*D_
  f16* wob   = wqkvb + (size_t)NQKV_ * D_; // D_*D_
  f16* qb    = wob + (size_t)D_ * D_;      // BHSD
  f16* kb    = qb + BHSD;                  // BHSD
  f16* vtb   = kb + BHSD;                  // BHSD (B,H,hd,S)
  f16* attnb = vtb + BHSD;                 // BHSD
  float2* tab = (float2*)(attnb + BHSD);   // S_*32 float2 = 512 KB
  // total ~92 MB of d_ws

  cast_kernel<<<(M_ * D_) / 2048, 256, 0, stream>>>(x, xb);
  cast_kernel<<<(NQKV_ * D_) / 2048, 256, 0, stream>>>(wqkv, wqkvb);
  cast_kernel<<<(D_ * D_) / 2048, 256, 0, stream>>>(wo, wob);
  trig_kernel<<<(S_ * 32) / 256, 256, 0, stream>>>(pos, tab);

  gemm_bt<0><<<(M_ / 128) * (NQKV_ / 128), 256, 0, stream>>>(
      xb, wqkvb, (void*)qb, tab, kb, vtb, M_, NQKV_, D_);

  attn_kernel<<<64 * 16, 256, 0, stream>>>(qb, kb, vtb, attnb);

  gemm_bt<1><<<(M_ / 128) * (D_ / 128), 256, 0, stream>>>(
      attnb, wob, (void*)out, nullptr, nullptr, nullptr, M_, D_, D_);
}

// Round 11
// 185.823 us; speedup vs baseline: 1.1666x; 1.0313x over previous
//
#include <hip/hip_runtime.h>

#define B_ 4
#define S_ 2048
#define D_ 1024
#define H_ 16
#define HD_ 64
#define M_ (B_*S_)      // 8192 rows
#define NQKV_ (3*D_)    // 3072

typedef _Float16 f16;
typedef __attribute__((ext_vector_type(4))) _Float16 f16x4;
typedef __attribute__((ext_vector_type(8))) _Float16 f16x8;
typedef __attribute__((ext_vector_type(4))) float f32x4;
typedef __attribute__((ext_vector_type(16))) float f32x16;
typedef __attribute__((ext_vector_type(2))) int i32x2;
typedef __attribute__((ext_vector_type(4))) int i32x4;

__device__ __forceinline__ void gload_lds16(const void* g, void* lds) {
  __builtin_amdgcn_global_load_lds(
      (const __attribute__((address_space(1))) void*)g,
      (__attribute__((address_space(3))) void*)lds, 16, 0, 0);
}

// ---------------- cast fp32 -> fp16, 8 elems/thread ----------------
__global__ void cast_kernel(const float* __restrict__ in, f16* __restrict__ out) {
  size_t i = (size_t)(blockIdx.x * 256 + threadIdx.x) * 8;
  float4 a = *reinterpret_cast<const float4*>(in + i);
  float4 b = *reinterpret_cast<const float4*>(in + i + 4);
  f16x8 o;
  o[0] = (f16)a.x; o[1] = (f16)a.y; o[2] = (f16)a.z; o[3] = (f16)a.w;
  o[4] = (f16)b.x; o[5] = (f16)b.y; o[6] = (f16)b.z; o[7] = (f16)b.w;
  *reinterpret_cast<f16x8*>(out + i) = o;
}

// ---------------- RoPE trig table: tab[s][t] = {cos,sin}(pos[s]*invf(t))
__global__ void trig_kernel(const int* __restrict__ pos, float2* __restrict__ tab) {
  int idx = blockIdx.x * 256 + threadIdx.x;   // S_*32 threads
  int s = idx >> 5, t = idx & 31;
  float p = (float)pos[s];
  float invf = exp2f((float)t * -0.4152410118609203f);  // -log2(10000)/32
  float sn, cs;
  sincosf(p * invf, &sn, &cs);
  tab[idx] = float2{cs, sn};
}

// ---------------- GEMM C[m,n] = sum_k A[m,k]*Bt[n,k] ----------------
// (unchanged from Round 10 — improved to <88 us)
// Residency-first counted-vmcnt ring-2: 128x128 tile, BK=32, 4 waves,
// LDS 32 KB -> 4 blocks/CU. iter t: STAGE(t+1); vmcnt(4); s_barrier;
// compute buf[t&1]; s_barrier.
template <int MODE>
__global__ __launch_bounds__(256, 4)
void gemm_bt(const f16* __restrict__ A, const f16* __restrict__ Bt,
             void* __restrict__ Cout, const float2* __restrict__ tab,
             f16* __restrict__ kout, f16* __restrict__ vtout,
             int M, int N, int K) {
  __shared__ __align__(16) f16 As[2][128 * 32];
  __shared__ __align__(16) f16 Bs[2][128 * 32];
  const int tid = threadIdx.x;
  const int w = tid >> 6, l = tid & 63;
  const int nM = M >> 7;
  const int bm = (int)(blockIdx.x % nM) << 7;
  const int bn = (int)(blockIdx.x / nM) << 7;
  const int wrow = (w >> 1) << 6;   // 0,64
  const int wcol = (w & 1) << 6;    // 0,64
  const int lr = l & 15;
  const int lk = (l >> 4) << 3;     // 0,8,16,24
  const int orow = (l >> 4) << 2;
  const int swzr = (lr & 3) << 3;   // read-side XOR (elems), 64B rows
  const int NT = K >> 5;            // 32

  f32x4 acc[4][4];
  #pragma unroll
  for (int i = 0; i < 4; ++i)
    #pragma unroll
    for (int j = 0; j < 4; ++j) acc[i][j] = f32x4{0.f, 0.f, 0.f, 0.f};

  const int srow4 = tid >> 2;            // 4 threads/row, 16B each
  const int ssw = ((tid & 3) * 8) ^ ((srow4 & 3) << 3);

#define STAGE(t_) do {                                                    \
    const int buf_ = (t_) & 1; const int k0_ = (t_) << 5;                 \
    _Pragma("unroll")                                                     \
    for (int p = 0; p < 2; ++p)                                           \
      gload_lds16(A + (size_t)(bm + p * 64 + srow4) * K + k0_ + ssw,      \
                  (void*)(&As[buf_][(p * 256 + tid) * 8]));               \
    _Pragma("unroll")                                                     \
    for (int p = 0; p < 2; ++p)                                           \
      gload_lds16(Bt + (size_t)(bn + p * 64 + srow4) * K + k0_ + ssw,     \
                  (void*)(&Bs[buf_][(p * 256 + tid) * 8]));               \
  } while (0)

  STAGE(0);

  for (int t = 0; t < NT; ++t) {
    if (t + 1 < NT) {
      STAGE(t + 1);
      asm volatile("s_waitcnt vmcnt(4)" ::: "memory");   // tile t landed
    } else {
      asm volatile("s_waitcnt vmcnt(0)" ::: "memory");
    }
    __builtin_amdgcn_sched_barrier(0);
    __builtin_amdgcn_s_barrier();       // tile t visible to all waves
    __builtin_amdgcn_sched_barrier(0);

    const f16* Asc = As[t & 1];
    const f16* Bsc = Bs[t & 1];
    f16x8 af[4], bf[4];
    #pragma unroll
    for (int mi = 0; mi < 4; ++mi)
      af[mi] = *reinterpret_cast<const f16x8*>(
          Asc + (wrow + mi * 16 + lr) * 32 + (lk ^ swzr));
    #pragma unroll
    for (int ni = 0; ni < 4; ++ni)
      bf[ni] = *reinterpret_cast<const f16x8*>(
          Bsc + (wcol + ni * 16 + lr) * 32 + (lk ^ swzr));
    #pragma unroll
    for (int mi = 0; mi < 4; ++mi)
      #pragma unroll
      for (int ni = 0; ni < 4; ++ni)
        acc[mi][ni] = __builtin_amdgcn_mfma_f32_16x16x32_f16(bf[ni], af[mi], acc[mi][ni], 0, 0, 0);

    __builtin_amdgcn_sched_barrier(0);
    __builtin_amdgcn_s_barrier();       // all reads of buf[t&1] done
    __builtin_amdgcn_sched_barrier(0);
  }
#undef STAGE

  if (MODE == 0) {
    const int which = bn >> 10;                    // uniform per block
    const int h = ((bn + wcol) >> 6) & (H_ - 1);   // uniform per wave
    if (which < 2) {                               // Q or K: fused RoPE
      f16* dst = which ? kout : (f16*)Cout;
      const float qs = which ? 1.0f : 0.125f * 1.4426950408889634f;  // (1/8)*log2e
      #pragma unroll
      for (int mi = 0; mi < 4; ++mi) {
        int m = bm + wrow + mi * 16 + lr;
        int b = m >> 11, s = m & (S_ - 1);
        size_t rowbase = ((size_t)(b * H_ + h) * S_ + s) * HD_;
        const float4* trow = reinterpret_cast<const float4*>(tab + (size_t)s * 32);
        #pragma unroll
        for (int ni = 0; ni < 4; ++ni) {
          int d0 = ni * 16 + orow;                 // multiple of 4
          float4 cssn = trow[d0 >> 2];
          float x0 = acc[mi][ni][0], x1 = acc[mi][ni][1];
          float x2 = acc[mi][ni][2], x3 = acc[mi][ni][3];
          f16x4 ov;
          ov[0] = (f16)((x0 * cssn.x - x1 * cssn.y) * qs);
          ov[1] = (f16)((x1 * cssn.x + x0 * cssn.y) * qs);
          ov[2] = (f16)((x2 * cssn.z - x3 * cssn.w) * qs);
          ov[3] = (f16)((x3 * cssn.z + x2 * cssn.w) * qs);
          *reinterpret_cast<f16x4*>(&dst[rowbase + d0]) = ov;
        }
      }
    } else {                                       // V: direct transposed write
      #pragma unroll
      for (int mi = 0; mi < 4; ++mi) {
        int m = bm + wrow + mi * 16 + lr;
        int b = m >> 11, s = m & (S_ - 1);
        size_t base = (size_t)(b * H_ + h) * (HD_ * S_) + s;
        #pragma unroll
        for (int ni = 0; ni < 4; ++ni)
          #pragma unroll
          for (int r = 0; r < 4; ++r)
            vtout[base + (size_t)(ni * 16 + orow + r) * S_] = (f16)acc[mi][ni][r];
      }
    }
  } else {
    float* C = (float*)Cout;
    #pragma unroll
    for (int mi = 0; mi < 4; ++mi) {
      int m = bm + wrow + mi * 16 + lr;
      #pragma unroll
      for (int ni = 0; ni < 4; ++ni) {
        int n = bn + wcol + ni * 16 + orow;
        *reinterpret_cast<float4*>(&C[(size_t)m * N + n]) =
            float4{acc[mi][ni][0], acc[mi][ni][1], acc[mi][ni][2], acc[mi][ni][3]};
      }
    }
  }
}

// ---------------- flash attention (causal), 32x32 MFMA form ---------
// Changes this round (VALU/LDS relief):
//  * P never touches LDS: PV B-fragment assembled in-register via the
//    layout identity kv = 16*ks + 8*hi_dest + j  ->  {own 4 regs} +
//    {partner lane l^32's 4 regs}; one __shfl_xor(32) per packed pair.
//    Removes 8 ds_write + 4 ds_read per wave-tile and the 16KB Ps
//    buffer (LDS 32->16 KB).
//  * T13 defer-max (THR=8, exp2 domain): skip o-rescale + m update
//    when __all(mloc <= m_run + 8); P bounded by 2^8, fits f16.
__global__ __launch_bounds__(256, 4)
void attn_kernel(const f16* __restrict__ q, const f16* __restrict__ k,
                 const f16* __restrict__ vt, f16* __restrict__ attn_out) {
  __shared__ __align__(16) f16 Ks[64 * 64];
  __shared__ __align__(16) f16 Vs[64 * 64];     // [d][kv]
  const int tid = threadIdx.x, wq = tid >> 6, l = tid & 63;
  const int lq = l & 31, hi = l >> 5;
  const int bh = blockIdx.x & 63;
  const int qt = 15 - (int)(blockIdx.x >> 6);   // heavy tiles first
  const int q0 = qt << 7;
  const size_t bhoff = (size_t)bh * (S_ * HD_);
  const size_t vtoff = (size_t)bh * (HD_ * S_);
  const int srow = tid >> 3;
  const int sc8 = (tid & 7) * 8;
  const int ssw = sc8 ^ ((srow & 7) << 3);      // swizzled source col
  const int swz = (lq & 7) << 3;                // read-side XOR
  const int h = bh & (H_ - 1), b = bh >> 4;
  const int wqmin = q0 + wq * 32;
  const int qrow = wqmin + lq;                  // this lane's q-row

  f16x8 qf[4];
  #pragma unroll
  for (int s = 0; s < 4; ++s)
    qf[s] = *reinterpret_cast<const f16x8*>(q + bhoff + (size_t)qrow * HD_ + s * 16 + hi * 8);

  f32x16 o[2];
  float m_run = -1e30f, l_run = 0.f;
  #pragma unroll
  for (int i = 0; i < 2; ++i)
    #pragma unroll
    for (int r = 0; r < 16; ++r) o[i][r] = 0.f;

  const int ntiles = 2 * qt + 2;
  for (int it = 0; it < ntiles; ++it) {
    const int kv0 = it << 6;
    __syncthreads();
    #pragma unroll
    for (int i = 0; i < 2; ++i) {
      gload_lds16(k + bhoff + (size_t)(kv0 + i * 32 + srow) * HD_ + ssw,
                  (void*)(Ks + (i * 256 + wq * 64) * 8));
      gload_lds16(vt + vtoff + (size_t)(i * 32 + srow) * S_ + kv0 + ssw,
                  (void*)(Vs + (i * 256 + wq * 64) * 8));
    }
    __syncthreads();

    if (kv0 <= wqmin + 31) {   // wave-uniform causal skip
      // S^T: D[col=q=lq][row = kh*32 + (r&3) + 8*(r>>2) + 4*hi]
      f32x16 sacc[2];
      #pragma unroll
      for (int kh = 0; kh < 2; ++kh) {
        #pragma unroll
        for (int r = 0; r < 16; ++r) sacc[kh][r] = 0.f;
        #pragma unroll
        for (int s = 0; s < 4; ++s) {
          f16x8 kf = *reinterpret_cast<const f16x8*>(
              Ks + (kh * 32 + lq) * 64 + ((s * 16 + hi * 8) ^ swz));
          sacc[kh] = __builtin_amdgcn_mfma_f32_32x32x16_f16(kf, qf[s], sacc[kh], 0, 0, 0);
        }
      }
      if (kv0 + 63 >= wqmin) {   // diagonal straddle: element mask
        #pragma unroll
        for (int kh = 0; kh < 2; ++kh)
          #pragma unroll
          for (int r = 0; r < 16; ++r) {
            int kvg = kv0 + kh * 32 + (r & 3) + 8 * (r >> 2) + 4 * hi;
            if (kvg > qrow) sacc[kh][r] = -1e30f;
          }
      }

      // online softmax with defer-max (T13, THR=8 in log2 units)
      float mloc = -1e30f;
      #pragma unroll
      for (int kh = 0; kh < 2; ++kh)
        #pragma unroll
        for (int r = 0; r < 16; ++r) mloc = fmaxf(mloc, sacc[kh][r]);
      mloc = fmaxf(mloc, __shfl_xor(mloc, 32));
      if (__any(mloc > m_run + 8.f)) {
        float mn = fmaxf(m_run, mloc);
        float scale = exp2f(m_run - mn);
        m_run = mn;
        l_run *= scale;
        #pragma unroll
        for (int i = 0; i < 2; ++i)
          #pragma unroll
          for (int r = 0; r < 16; ++r) o[i][r] *= scale;
      }
      float sloc = 0.f;
      #pragma unroll
      for (int kh = 0; kh < 2; ++kh)
        #pragma unroll
        for (int r = 0; r < 16; ++r) {
          sacc[kh][r] = exp2f(sacc[kh][r] - m_run);
          sloc += sacc[kh][r];
        }
      sloc += __shfl_xor(sloc, 32);
      l_run += sloc;

      // P -> PV B-fragments fully in-register:
      // pf[ks][j] = P[lq][16*ks + 8*hi + j]; element j<4 comes from the
      // hi=0 lane of the pair, j>=4 from the hi=1 lane, both at regs
      // (ks&1)*8 + {0..3} (pA) / + {4..7} (pB) of sacc[ks>>1].
      f16x8 pf[4];
      #pragma unroll
      for (int ks = 0; ks < 4; ++ks) {
        const int khh = ks >> 1;
        f16x4 pA, pB;
        #pragma unroll
        for (int r = 0; r < 4; ++r) {
          pA[r] = (f16)sacc[khh][(ks & 1) * 8 + r];
          pB[r] = (f16)sacc[khh][(ks & 1) * 8 + 4 + r];
        }
        i32x2 ia = __builtin_bit_cast(i32x2, pA);
        i32x2 ib = __builtin_bit_cast(i32x2, pB);
        i32x2 oth, rcv, lo2, hh2;
        oth.x = hi ? ia.x : ib.x;
        oth.y = hi ? ia.y : ib.y;
        rcv.x = __shfl_xor(oth.x, 32);
        rcv.y = __shfl_xor(oth.y, 32);
        lo2.x = hi ? rcv.x : ia.x;
        lo2.y = hi ? rcv.y : ia.y;
        hh2.x = hi ? ib.x : rcv.x;
        hh2.y = hi ? ib.y : rcv.y;
        i32x4 full{lo2.x, lo2.y, hh2.x, hh2.y};
        pf[ks] = __builtin_bit_cast(f16x8, full);
      }

      // O^T += V^T @ P^T
      #pragma unroll
      for (int dh = 0; dh < 2; ++dh)
        #pragma unroll
        for (int s2 = 0; s2 < 4; ++s2) {
          f16x8 vf = *reinterpret_cast<const f16x8*>(
              Vs + (dh * 32 + lq) * 64 + ((s2 * 16 + hi * 8) ^ swz));
          o[dh] = __builtin_amdgcn_mfma_f32_32x32x16_f16(vf, pf[s2], o[dh], 0, 0, 0);
        }
    }
  }

  // epilogue: O^T[d][q]: d = dh*32 + (r&3) + 8*(r>>2) + 4*hi, q = lq
  float rl = 1.0f / l_run;
  #pragma unroll
  for (int dh = 0; dh < 2; ++dh)
    #pragma unroll
    for (int qd = 0; qd < 4; ++qd) {
      f16x4 ov;
      #pragma unroll
      for (int r = 0; r < 4; ++r) ov[r] = (f16)(o[dh][qd * 4 + r] * rl);
      int d0 = dh * 32 + qd * 8 + hi * 4;
      *reinterpret_cast<f16x4*>(
          &attn_out[(size_t)(b * S_ + qrow) * D_ + h * HD_ + d0]) = ov;
    }
}

// ---------------- launch --------------------------------------------
extern "C" void kernel_launch(void* const* d_in, const int* in_sizes, int n_in,
                              void* d_out, int out_size, void* d_ws, size_t ws_size,
                              hipStream_t stream) {
  const float* x    = (const float*)d_in[0];
  const int*   pos  = (const int*)d_in[1];
  const float* wqkv = (const float*)d_in[2];
  const float* wo   = (const float*)d_in[3];
  float* out = (float*)d_out;

  const size_t BHSD = (size_t)B_ * H_ * S_ * HD_;   // 8388608
  f16* xb    = (f16*)d_ws;                 // M_*D_
  f16* wqkvb = xb + (size_t)M_ * D_;       // NQKV_*D_
  f16* wob   = wqkvb + (size_t)NQKV_ * D_; // D_*D_
  f16* qb    = wob + (size_t)D_ * D_;      // BHSD
  f16* kb    = qb + BHSD;                  // BHSD
  f16* vtb   = kb + BHSD;                  // BHSD (B,H,hd,S)
  f16* attnb = vtb + BHSD;                 // BHSD
  float2* tab = (float2*)(attnb + BHSD);   // S_*32 float2 = 512 KB
  // total ~92 MB of d_ws

  cast_kernel<<<(M_ * D_) / 2048, 256, 0, stream>>>(x, xb);
  cast_kernel<<<(NQKV_ * D_) / 2048, 256, 0, stream>>>(wqkv, wqkvb);
  cast_kernel<<<(D_ * D_) / 2048, 256, 0, stream>>>(wo, wob);
  trig_kernel<<<(S_ * 32) / 256, 256, 0, stream>>>(pos, tab);

  gemm_bt<0><<<(M_ / 128) * (NQKV_ / 128), 256, 0, stream>>>(
      xb, wqkvb, (void*)qb, tab, kb, vtb, M_, NQKV_, D_);

  attn_kernel<<<64 * 16, 256, 0, stream>>>(qb, kb, vtb, attnb);

  gemm_bt<1><<<(M_ / 128) * (D_ / 128), 256, 0, stream>>>(
      attnb, wob, (void*)out, nullptr, nullptr, nullptr, M_, D_, D_);
}